// Round 6
// baseline (398.113 us; speedup 1.0000x reference)
//
#include <hip/hip_runtime.h>
#include <hip/hip_bf16.h>

typedef unsigned short u16;
typedef __bf16 bf16x8 __attribute__((ext_vector_type(8)));
typedef float f32x4 __attribute__((ext_vector_type(4)));

__device__ __forceinline__ u16 f2bf(float f) {
    union { float f; unsigned int u; } v; v.f = f;
    unsigned int u = v.u;
    unsigned int r = (u + 0x7fffu + ((u >> 16) & 1u)) >> 16;
    return (u16)r;
}
__device__ __forceinline__ float bf2f(u16 b) {
    union { unsigned int u; float f; } v; v.u = ((unsigned int)b) << 16;
    return v.f;
}

__device__ __forceinline__ void glds16(const u16* g, u16* l) {
    __builtin_amdgcn_global_load_lds(
        (__attribute__((address_space(1))) void*)(g),
        (__attribute__((address_space(3))) void*)(l), 16, 0, 0);
}

// ---------------- cast fp32 -> bf16 (vectorized) ----------------
__global__ __launch_bounds__(256) void cast_bf16_kernel(const float* __restrict__ src,
                                                        u16* __restrict__ dst, int n4) {
    int i = blockIdx.x * 256 + threadIdx.x;
    if (i >= n4) return;
    float4 v = ((const float4*)src)[i];
    ushort4 o;
    o.x = f2bf(v.x); o.y = f2bf(v.y); o.z = f2bf(v.z); o.w = f2bf(v.w);
    ((ushort4*)dst)[i] = o;
}

// ---------------- transpose+cast weights: WT[n][k] = W[k][n] ----------------
__global__ __launch_bounds__(256) void transpose_cast_kernel(
    const float* __restrict__ Wq, const float* __restrict__ Wk, const float* __restrict__ Wv,
    const float* __restrict__ Wg, const float* __restrict__ Wo,
    u16* __restrict__ WqT, u16* __restrict__ WkvT, u16* __restrict__ WgT, u16* __restrict__ WoT) {
    __shared__ float tile[32][33];
    const float* src; u16* dst;
    switch (blockIdx.z) {
        case 0: src = Wq; dst = WqT; break;
        case 1: src = Wk; dst = WkvT; break;
        case 2: src = Wv; dst = WkvT + (size_t)1024 * 1024; break;
        case 3: src = Wg; dst = WgT; break;
        default: src = Wo; dst = WoT; break;
    }
    int n0 = blockIdx.x * 32, k0 = blockIdx.y * 32;
    int tx = threadIdx.x, ty = threadIdx.y;   // (32, 8)
    #pragma unroll
    for (int j = 0; j < 4; j++)
        tile[ty + j * 8][tx] = src[(size_t)(k0 + ty + j * 8) * 1024 + n0 + tx];
    __syncthreads();
    #pragma unroll
    for (int j = 0; j < 4; j++)
        dst[(size_t)(n0 + ty + j * 8) * 1024 + k0 + tx] = f2bf(tile[tx][ty + j * 8]);
}

// ---------------- 128^2 bf16 MFMA GEMM (m97 structure) ----------------
template <int EPI>
__global__ __launch_bounds__(256) void gemm_bf16(
    const u16* __restrict__ A, const u16* __restrict__ B, int ldc,
    u16* __restrict__ Cbf, const float* __restrict__ bias,
    const u16* __restrict__ mul_src, const float* __restrict__ add_src,
    float* __restrict__ Cf) {
    constexpr int K = 1024;
    const int tid = threadIdx.x;
    const int w = tid >> 6, l = tid & 63;
    const int lr = l & 15, lg = l >> 4;
    const int wr = w >> 1, wc = w & 1;
    const int m0 = blockIdx.y * 128, n0 = blockIdx.x * 128;

    __shared__ u16 As[128 * 64];
    __shared__ u16 Bs[128 * 64];

    const f32x4 fz = {0.f, 0.f, 0.f, 0.f};
    f32x4 acc[4][4];
    #pragma unroll
    for (int i = 0; i < 4; i++)
        #pragma unroll
        for (int j = 0; j < 4; j++) acc[i][j] = fz;

    const int lane_row = l >> 3;
    const int lane_sl  = l & 7;
    const int src_ch   = lane_sl ^ lane_row;
    const u16* Ab = A + (size_t)(m0 + w * 32 + lane_row) * K + src_ch * 8;
    const u16* Bb = B + (size_t)(n0 + w * 32 + lane_row) * K + src_ch * 8;

    for (int kt = 0; kt < K; kt += 64) {
        __syncthreads();
        #pragma unroll
        for (int j = 0; j < 4; j++) {
            glds16(Ab + (size_t)j * 8 * K + kt, As + (w * 32 + j * 8) * 64);
            glds16(Bb + (size_t)j * 8 * K + kt, Bs + (w * 32 + j * 8) * 64);
        }
        __syncthreads();
        #pragma unroll
        for (int kk = 0; kk < 2; kk++) {
            bf16x8 af[4], bfr[4];
            #pragma unroll
            for (int mi = 0; mi < 4; mi++) {
                int row = wr * 64 + mi * 16 + lr;
                int ch = (kk * 4 + lg) ^ (row & 7);
                af[mi] = *(const bf16x8*)(As + row * 64 + ch * 8);
            }
            #pragma unroll
            for (int ni = 0; ni < 4; ni++) {
                int row = wc * 64 + ni * 16 + lr;
                int ch = (kk * 4 + lg) ^ (row & 7);
                bfr[ni] = *(const bf16x8*)(Bs + row * 64 + ch * 8);
            }
            #pragma unroll
            for (int mi = 0; mi < 4; mi++)
                #pragma unroll
                for (int ni = 0; ni < 4; ni++)
                    acc[mi][ni] = __builtin_amdgcn_mfma_f32_16x16x32_bf16(
                        af[mi], bfr[ni], acc[mi][ni], 0, 0, 0);
        }
    }

    #pragma unroll
    for (int mi = 0; mi < 4; mi++) {
        #pragma unroll
        for (int ni = 0; ni < 4; ni++) {
            #pragma unroll
            for (int r = 0; r < 4; r++) {
                int gm = m0 + wr * 64 + mi * 16 + lg * 4 + r;
                int gn = n0 + wc * 64 + ni * 16 + lr;
                float v = acc[mi][ni][r];
                if (EPI == 0) {
                    Cbf[(size_t)gm * ldc + gn] = f2bf(v);
                } else if (EPI == 2) {
                    float g = v + bias[gn];
                    float a = bf2f(mul_src[(size_t)gm * ldc + gn]);
                    float sg = 1.f / (1.f + __expf(-g));
                    Cbf[(size_t)gm * ldc + gn] = f2bf(a * sg);
                } else {
                    Cf[(size_t)gm * ldc + gn] = v + bias[gn] + add_src[(size_t)gm * ldc + gn];
                }
            }
        }
    }
}

// ---------------- hidden column-sum, stage 1: 16-row partials ----------------
__global__ __launch_bounds__(256) void hsum1_kernel(const float* __restrict__ hidden,
                                                    float* __restrict__ part) {
    int b = blockIdx.x, chunk = blockIdx.y;   // (2, 128)
    int tid = threadIdx.x;
    const float4* src = (const float4*)(hidden + ((size_t)b * 2048 + chunk * 16) * 1024) + tid;
    float4 acc = {0.f, 0.f, 0.f, 0.f};
    #pragma unroll
    for (int r = 0; r < 16; r++) {
        float4 v = src[r * 256];
        acc.x += v.x; acc.y += v.y; acc.z += v.z; acc.w += v.w;
    }
    ((float4*)(part + ((size_t)b * 128 + chunk) * 1024))[tid] = acc;
}

// ---------------- stage 2: reduce 128 partials -> mean ----------------
__global__ __launch_bounds__(256) void hsum2_kernel(const float* __restrict__ part,
                                                    float* __restrict__ hm) {
    int b = blockIdx.x, tid = threadIdx.x;
    const float4* src = (const float4*)(part + (size_t)b * 128 * 1024) + tid;
    float4 acc = {0.f, 0.f, 0.f, 0.f};
    for (int c = 0; c < 128; c++) {
        float4 v = src[c * 256];
        acc.x += v.x; acc.y += v.y; acc.z += v.z; acc.w += v.w;
    }
    const float inv = 1.f / 2048.f;
    acc.x *= inv; acc.y *= inv; acc.z *= inv; acc.w *= inv;
    ((float4*)(hm + (size_t)b * 1024))[tid] = acc;
}

// ---------------- qz: qsum = hmean @ Wq_h ; z = qsum @ Wk_h^T (per bh) ----------------
__global__ __launch_bounds__(256) void qz_kernel(const float* __restrict__ hm,
                                                 const u16* __restrict__ WqT,
                                                 const u16* __restrict__ WkT,
                                                 u16* __restrict__ z_bf) {
    int bh = blockIdx.x, b = bh >> 4, h = bh & 15;
    int tid = threadIdx.x;
    __shared__ float hm_l[1024];
    __shared__ float qs_l[64];
    __shared__ float red[256];
    ((float4*)hm_l)[tid] = ((const float4*)(hm + (size_t)b * 1024))[tid];
    __syncthreads();
    {
        int d = tid >> 2, q = tid & 3;
        const u16* wq = WqT + (size_t)(h * 64 + d) * 1024 + q * 256;
        float a = 0.f;
        for (int i = 0; i < 256; i += 8) {
            uint4 u = *(const uint4*)(wq + i);
            const u16* p = (const u16*)&u;
            #pragma unroll
            for (int j = 0; j < 8; j++) a += bf2f(p[j]) * hm_l[q * 256 + i + j];
        }
        red[tid] = a;
    }
    __syncthreads();
    if (tid < 64)
        qs_l[tid] = red[tid * 4] + red[tid * 4 + 1] + red[tid * 4 + 2] + red[tid * 4 + 3];
    __syncthreads();
    {
        float z0 = 0.f, z1 = 0.f, z2 = 0.f, z3 = 0.f;
        for (int d = 0; d < 64; d++) {
            float qs = qs_l[d];
            const u16* wk = WkT + (size_t)(h * 64 + d) * 1024 + tid * 4;
            uint2 u = *(const uint2*)wk;
            const u16* p = (const u16*)&u;
            z0 += qs * bf2f(p[0]); z1 += qs * bf2f(p[1]);
            z2 += qs * bf2f(p[2]); z3 += qs * bf2f(p[3]);
        }
        ushort4 o;
        o.x = f2bf(z0); o.y = f2bf(z1); o.z = f2bf(z2); o.w = f2bf(z3);
        *(ushort4*)(z_bf + (size_t)bh * 1024 + tid * 4) = o;
    }
}

// ---------------- score via MFMA: score[b*16+h][kv] = z[bh] . enc[kv] ----------------
__global__ __launch_bounds__(256) void score_mfma_kernel(const u16* __restrict__ ebf,
                                                         const u16* __restrict__ z_bf,
                                                         float* __restrict__ score) {
    const int b = blockIdx.y, kv0 = blockIdx.x * 256;
    const int tid = threadIdx.x, w = tid >> 6, l = tid & 63;
    const int lr = l & 15, lg = l >> 4;
    __shared__ u16 z_lds[16 * 1024];
    __shared__ u16 e_lds[256 * 64];
    {
        int row = tid >> 4, cg = tid & 15;
        const u16* src = z_bf + (size_t)(b * 16 + row) * 1024 + cg * 64;
        #pragma unroll
        for (int i = 0; i < 8; i++) {
            uint4 u = *(const uint4*)(src + i * 8);
            int ch = cg * 8 + i;
            *(uint4*)(z_lds + row * 1024 + (ch ^ (row & 7)) * 8) = u;
        }
    }
    const int lane_row = l >> 3, src_ch = (l & 7) ^ lane_row;
    const f32x4 fz = {0.f, 0.f, 0.f, 0.f};
    f32x4 acc[4];
    #pragma unroll
    for (int ni = 0; ni < 4; ni++) acc[ni] = fz;

    for (int kt = 0; kt < 1024; kt += 64) {
        __syncthreads();
        #pragma unroll
        for (int j = 0; j < 8; j++) {
            const u16* src = ebf + (size_t)(b * 16384 + kv0 + w * 64 + j * 8 + lane_row) * 1024 + kt + src_ch * 8;
            glds16(src, e_lds + (w * 64 + j * 8) * 64);
        }
        __syncthreads();
        #pragma unroll
        for (int ks = 0; ks < 2; ks++) {
            int chg = (kt >> 3) + ks * 4 + lg;
            bf16x8 af = *(const bf16x8*)(z_lds + lr * 1024 + (chg ^ (lr & 7)) * 8);
            #pragma unroll
            for (int ni = 0; ni < 4; ni++) {
                int row = w * 64 + ni * 16 + lr;
                bf16x8 bf_ = *(const bf16x8*)(e_lds + row * 64 + (((ks * 4 + lg) ^ (lr & 7))) * 8);
                acc[ni] = __builtin_amdgcn_mfma_f32_16x16x32_bf16(af, bf_, acc[ni], 0, 0, 0);
            }
        }
    }
    #pragma unroll
    for (int ni = 0; ni < 4; ni++)
        #pragma unroll
        for (int r = 0; r < 4; r++)
            score[(size_t)(b * 16 + lg * 4 + r) * 16384 + kv0 + w * 64 + ni * 16 + lr] = acc[ni][r];
}

// ---------------- radix top-2048 select per (b,h) ----------------
__global__ __launch_bounds__(256) void select_kernel(const float* __restrict__ score,
                                                     int* __restrict__ sel_idx) {
    int bh = blockIdx.x;
    const float* sc = score + (size_t)bh * 16384;
    __shared__ int hist[256];
    __shared__ int bc[4];
    int tid = threadIdx.x;
    if (tid == 0) { bc[0] = 0; bc[1] = 2048; bc[2] = 0; bc[3] = 0; }
    __syncthreads();
    for (int shift = 24; shift >= 0; shift -= 8) {
        hist[tid] = 0;
        __syncthreads();
        unsigned int prefix = (unsigned int)bc[0];
        unsigned int hi_mask = (shift == 24) ? 0u : (0xFFFFFFFFu << (shift + 8));
        for (int i = tid; i < 16384; i += 256) {
            unsigned int b = __float_as_uint(sc[i]);
            unsigned int ui = (b & 0x80000000u) ? ~b : (b | 0x80000000u);
            if ((ui & hi_mask) == (prefix & hi_mask))
                atomicAdd(&hist[(ui >> shift) & 0xff], 1);
        }
        __syncthreads();
        if (tid == 0) {
            int want = bc[1], acc = 0, d = 0;
            for (int dd = 255; dd >= 0; dd--) {
                acc += hist[dd];
                if (acc >= want) { d = dd; break; }
            }
            bc[1] = want - (acc - hist[d]);
            bc[0] = (int)(prefix | ((unsigned int)d << shift));
        }
        __syncthreads();
    }
    unsigned int uthr = (unsigned int)bc[0];
    int n_eq = bc[1];
    int base_eq = 2048 - n_eq;
    int* out = sel_idx + (size_t)bh * 2048;
    for (int i = tid; i < 16384; i += 256) {
        unsigned int b = __float_as_uint(sc[i]);
        unsigned int ui = (b & 0x80000000u) ? ~b : (b | 0x80000000u);
        if (ui > uthr) {
            int p = atomicAdd(&bc[2], 1);
            out[p] = i;
        } else if (ui == uthr) {
            int p = atomicAdd(&bc[3], 1);
            if (p < n_eq) out[base_eq + p] = i;
        }
    }
}

// ---------------- selected projection: K_sel[t][d] and V_selT[d][t] (chunk-swizzled) ----
__global__ __launch_bounds__(256) void selproj_kernel(const u16* __restrict__ ebf,
                                                      const u16* __restrict__ WkvT,
                                                      const int* __restrict__ sel_idx,
                                                      u16* __restrict__ k_sel,
                                                      u16* __restrict__ v_selT) {
    const int bh = blockIdx.y, b = bh >> 4, h = bh & 15;
    const int t0 = blockIdx.x * 128;
    const int tid = threadIdx.x, w = tid >> 6, l = tid & 63;
    const int lr = l & 15, lg = l >> 4;
    const int lane_row = l >> 3, src_ch = (l & 7) ^ lane_row;

    __shared__ u16 e_lds[128 * 64];
    __shared__ u16 w_lds[128 * 64];

    int encrow[4], wrow[4];
    #pragma unroll
    for (int j = 0; j < 4; j++) {
        int t = t0 + w * 32 + j * 8 + lane_row;
        encrow[j] = b * 16384 + sel_idx[(size_t)bh * 2048 + t];
        int r = w * 32 + j * 8 + lane_row;
        wrow[j] = (r < 64) ? (h * 64 + r) : (1024 + h * 64 + (r & 63));
    }

    const f32x4 fz = {0.f, 0.f, 0.f, 0.f};
    f32x4 acc_k[2][4], acc_v[8];
    #pragma unroll
    for (int i = 0; i < 2; i++)
        #pragma unroll
        for (int j = 0; j < 4; j++) acc_k[i][j] = fz;
    #pragma unroll
    for (int i = 0; i < 8; i++) acc_v[i] = fz;

    for (int kt = 0; kt < 1024; kt += 64) {
        __syncthreads();
        #pragma unroll
        for (int j = 0; j < 4; j++) {
            glds16(ebf + (size_t)encrow[j] * 1024 + kt + src_ch * 8, e_lds + (w * 32 + j * 8) * 64);
            glds16(WkvT + (size_t)wrow[j] * 1024 + kt + src_ch * 8, w_lds + (w * 32 + j * 8) * 64);
        }
        __syncthreads();
        #pragma unroll
        for (int ks = 0; ks < 2; ks++) {
            bf16x8 ae[2];
            #pragma unroll
            for (int mi = 0; mi < 2; mi++) {
                int row = w * 32 + mi * 16 + lr;
                ae[mi] = *(const bf16x8*)(e_lds + row * 64 + (((ks * 4 + lg) ^ (row & 7))) * 8);
            }
            bf16x8 aw;
            {
                int row = 64 + w * 16 + lr;
                aw = *(const bf16x8*)(w_lds + row * 64 + (((ks * 4 + lg) ^ (row & 7))) * 8);
            }
            #pragma unroll
            for (int ni = 0; ni < 4; ni++) {
                int row = ni * 16 + lr;
                bf16x8 bw = *(const bf16x8*)(w_lds + row * 64 + (((ks * 4 + lg) ^ (row & 7))) * 8);
                acc_k[0][ni] = __builtin_amdgcn_mfma_f32_16x16x32_bf16(ae[0], bw, acc_k[0][ni], 0, 0, 0);
                acc_k[1][ni] = __builtin_amdgcn_mfma_f32_16x16x32_bf16(ae[1], bw, acc_k[1][ni], 0, 0, 0);
            }
            #pragma unroll
            for (int ni = 0; ni < 8; ni++) {
                int row = ni * 16 + lr;
                bf16x8 be = *(const bf16x8*)(e_lds + row * 64 + (((ks * 4 + lg) ^ (row & 7))) * 8);
                acc_v[ni] = __builtin_amdgcn_mfma_f32_16x16x32_bf16(aw, be, acc_v[ni], 0, 0, 0);
            }
        }
    }

    u16* kb = k_sel + (size_t)bh * 2048 * 64;
    #pragma unroll
    for (int mi = 0; mi < 2; mi++)
        #pragma unroll
        for (int ni = 0; ni < 4; ni++)
            #pragma unroll
            for (int r = 0; r < 4; r++) {
                int t = t0 + w * 32 + mi * 16 + lg * 4 + r;
                int d = ni * 16 + lr;
                kb[(size_t)t * 64 + (((d >> 3) ^ (t & 7)) * 8) + (d & 7)] = f2bf(acc_k[mi][ni][r]);
            }
    u16* vb = v_selT + (size_t)bh * 64 * 2048;
    #pragma unroll
    for (int ni = 0; ni < 8; ni++)
        #pragma unroll
        for (int r = 0; r < 4; r++) {
            int d = w * 16 + lg * 4 + r;
            int t = t0 + ni * 16 + lr;
            int tl = t & 63;
            vb[(size_t)d * 2048 + (t & ~63) + ((((tl >> 3) ^ (d & 7))) * 8) + (tl & 7)] =
                f2bf(acc_v[ni][r]);
        }
}

// ---------------- flash attention (2-phase pipelined, dbuf K/V) ----------------
__global__ __launch_bounds__(256) void attn_kernel(
    const u16* __restrict__ q_bf, const u16* __restrict__ k_sel,
    const u16* __restrict__ v_selT, u16* __restrict__ attn_out) {
    const int bh = blockIdx.y, b = bh >> 4, h = bh & 15;
    const int q0 = blockIdx.x * 64;
    const int tid = threadIdx.x, w = tid >> 6, l = tid & 63;
    const int lr = l & 15, lg = l >> 4;
    const int lk = lr & 7;
    const float SC = 0.18033688011f;   // 0.125 * log2(e)
    const float THR = 11.0f;

    __shared__ u16 k_lds[2][64 * 64];
    __shared__ u16 vt_lds[2][64 * 64];
    __shared__ __bf16 p_lds[4][16][68];   // row stride 136B -> conflict-free writes

    const u16* qb = q_bf + ((size_t)b * 2048 + q0 + w * 16 + lr) * 1024 + h * 64;
    bf16x8 qf0 = *(const bf16x8*)(qb + lg * 8);
    bf16x8 qf1 = *(const bf16x8*)(qb + 32 + lg * 8);

    const f32x4 fz = {0.f, 0.f, 0.f, 0.f};
    f32x4 o[4];
    #pragma unroll
    for (int f = 0; f < 4; f++) o[f] = fz;
    float mm[4] = {-1e30f, -1e30f, -1e30f, -1e30f};
    float l_run[4] = {0.f, 0.f, 0.f, 0.f};

    const u16* kb  = k_sel + (size_t)bh * 2048 * 64;
    const u16* vtb = v_selT + (size_t)bh * 64 * 2048;

    auto stage = [&](int it, int buf) {
        const int t0s = it * 64;
        const u16* ksrc = kb + (size_t)(t0s + w * 16) * 64 + (size_t)l * 8;
        glds16(ksrc,       k_lds[buf] + (w * 16) * 64);
        glds16(ksrc + 512, k_lds[buf] + (w * 16 + 8) * 64);
        const u16* vsrc = vtb + (size_t)(w * 16 + (l >> 3)) * 2048 + t0s + (l & 7) * 8;
        glds16(vsrc,            vt_lds[buf] + (w * 16) * 64);
        glds16(vsrc + 8 * 2048, vt_lds[buf] + (w * 16 + 8) * 64);
    };

    stage(0, 0);
    __syncthreads();   // compiler drains vmcnt before barrier

    #pragma unroll 1
    for (int it = 0; it < 32; ++it) {
        const int cur = it & 1;
        if (it + 1 < 32) stage(it + 1, cur ^ 1);   // issue next tile EARLY

        // QK^T on buf[cur]
        f32x4 s[4];
        #pragma unroll
        for (int c = 0; c < 4; c++) s[c] = fz;
        __builtin_amdgcn_s_setprio(1);
        #pragma unroll
        for (int c = 0; c < 4; c++) {
            const u16* krow = k_lds[cur] + (c * 16 + lr) * 64;
            bf16x8 kf0 = *(const bf16x8*)(krow + (lg ^ lk) * 8);
            s[c] = __builtin_amdgcn_mfma_f32_16x16x32_bf16(qf0, kf0, s[c], 0, 0, 0);
            bf16x8 kf1 = *(const bf16x8*)(krow + (((4 + lg) ^ lk)) * 8);
            s[c] = __builtin_amdgcn_mfma_f32_16x16x32_bf16(qf1, kf1, s[c], 0, 0, 0);
        }
        __builtin_amdgcn_s_setprio(0);

        float mx[4];
        #pragma unroll
        for (int r = 0; r < 4; r++) {
            float m0 = fmaxf(fmaxf(s[0][r], s[1][r]), fmaxf(s[2][r], s[3][r]));
            m0 = fmaxf(m0, __shfl_xor(m0, 1));
            m0 = fmaxf(m0, __shfl_xor(m0, 2));
            m0 = fmaxf(m0, __shfl_xor(m0, 4));
            m0 = fmaxf(m0, __shfl_xor(m0, 8));
            mx[r] = m0 * SC;
        }
        bool need = false;
        #pragma unroll
        for (int r = 0; r < 4; r++) need = need || (mx[r] > mm[r] + THR);
        if (__any(need)) {
            #pragma unroll
            for (int r = 0; r < 4; r++) {
                float mn = fmaxf(mm[r], mx[r]);
                float al = __builtin_amdgcn_exp2f(mm[r] - mn);
                mm[r] = mn;
                l_run[r] *= al;
                #pragma unroll
                for (int f = 0; f < 4; f++) o[f][r] *= al;
            }
        }
        float rs[4] = {0.f, 0.f, 0.f, 0.f};
        #pragma unroll
        for (int c = 0; c < 4; c++) {
            #pragma unroll
            for (int r = 0; r < 4; r++) {
                float p = __builtin_amdgcn_exp2f(__builtin_fmaf(s[c][r], SC, -mm[r]));
                rs[r] += p;
                p_lds[w][lg * 4 + r][c * 16 + lr] = (__bf16)p;
            }
        }
        #pragma unroll
        for (int r = 0; r < 4; r++) {
            rs[r] += __shfl_xor(rs[r], 1);
            rs[r] += __shfl_xor(rs[r], 2);
            rs[r] += __shfl_xor(rs[r], 4);
            rs[r] += __shfl_xor(rs[r], 8);
            l_run[r] += rs[r];
        }

        // PV on buf[cur]
        __builtin_amdgcn_s_setprio(1);
        #pragma unroll
        for (int kk = 0; kk < 2; kk++) {
            bf16x8 ap = *(const bf16x8*)(&p_lds[w][lr][kk * 32 + lg * 8]);
            #pragma unroll
            for (int f = 0; f < 4; f++) {
                const u16* vrow = vt_lds[cur] + (f * 16 + lr) * 64;
                bf16x8 bv = *(const bf16x8*)(vrow + (((kk * 4 + lg) ^ lk)) * 8);
                o[f] = __builtin_amdgcn_mfma_f32_16x16x32_bf16(ap, bv, o[f], 0, 0, 0);
            }
        }
        __builtin_amdgcn_s_setprio(0);

        __syncthreads();   // single barrier per tile (drains staged loads, ~600cy after issue)
    }

    float invl[4];
    #pragma unroll
    for (int r = 0; r < 4; r++) invl[r] = 1.f / l_run[r];
    u16* ob = attn_out + ((size_t)b * 2048 + q0 + w * 16 + lg * 4) * 1024 + h * 64 + lr;
    #pragma unroll
    for (int f = 0; f < 4; f++) {
        #pragma unroll
        for (int r = 0; r < 4; r++) {
            __bf16 hv = (__bf16)(o[f][r] * invl[r]);
            ob[(size_t)r * 1024 + f * 16] = *(u16*)&hv;
        }
    }
}

// ---------------- launcher ----------------
extern "C" void kernel_launch(void* const* d_in, const int* in_sizes, int n_in,
                              void* d_out, int out_size, void* d_ws, size_t ws_size,
                              hipStream_t stream) {
    const float* hidden = (const float*)d_in[0];
    const float* enc    = (const float*)d_in[1];
    const float* Wq = (const float*)d_in[2];
    const float* Wk = (const float*)d_in[3];
    const float* Wv = (const float*)d_in[4];
    const float* Wo = (const float*)d_in[5];
    const float* bo = (const float*)d_in[6];
    const float* Wg = (const float*)d_in[7];
    const float* bg = (const float*)d_in[8];
    float* out = (float*)d_out;

    char* ws = (char*)d_ws;
    size_t off = 0;
    auto alloc = [&](size_t bytes) -> char* {
        char* p = ws + off;
        off += (bytes + 255) & ~(size_t)255;
        return p;
    };
    u16* hbf   = (u16*)alloc(4096ull * 1024 * 2);
    u16* ebf   = (u16*)alloc(32768ull * 1024 * 2);
    u16* WqT   = (u16*)alloc(1024ull * 1024 * 2);
    u16* WkvT  = (u16*)alloc(2048ull * 1024 * 2);
    u16* WgT   = (u16*)alloc(1024ull * 1024 * 2);
    u16* WoT   = (u16*)alloc(1024ull * 1024 * 2);
    u16* q_bf  = (u16*)alloc(4096ull * 1024 * 2);
    float* hm  = (float*)alloc(2ull * 1024 * 4);
    float* part = (float*)alloc(2ull * 128 * 1024 * 4);
    u16* z_bf  = (u16*)alloc(32ull * 1024 * 2);
    float* scor = (float*)alloc(32ull * 16384 * 4);
    int* sel    = (int*)alloc(32ull * 2048 * 4);
    u16* ksel   = (u16*)alloc(32ull * 2048 * 64 * 2);
    u16* vT     = (u16*)alloc(32ull * 64 * 2048 * 2);
    u16* attn   = (u16*)alloc(4096ull * 1024 * 2);
    u16* gate   = (u16*)alloc(4096ull * 1024 * 2);
    (void)ws_size; (void)in_sizes; (void)n_in; (void)out_size;

    hsum1_kernel<<<dim3(2, 128), 256, 0, stream>>>(hidden, part);
    hsum2_kernel<<<2, 256, 0, stream>>>(part, hm);
    cast_bf16_kernel<<<4096, 256, 0, stream>>>(hidden, hbf, 1048576);
    cast_bf16_kernel<<<32768, 256, 0, stream>>>(enc, ebf, 8388608);
    transpose_cast_kernel<<<dim3(32, 32, 5), dim3(32, 8), 0, stream>>>(
        Wq, Wk, Wv, Wg, Wo, WqT, WkvT, WgT, WoT);

    qz_kernel<<<32, 256, 0, stream>>>(hm, WqT, WkvT, z_bf);
    score_mfma_kernel<<<dim3(64, 2), 256, 0, stream>>>(ebf, z_bf, scor);
    select_kernel<<<32, 256, 0, stream>>>(scor, sel);
    selproj_kernel<<<dim3(16, 32), 256, 0, stream>>>(ebf, WkvT, sel, ksel, vT);

    gemm_bf16<0><<<dim3(8, 32), 256, 0, stream>>>(hbf, WqT, 1024, q_bf, nullptr, nullptr, nullptr, nullptr);
    attn_kernel<<<dim3(32, 32), 256, 0, stream>>>(q_bf, ksel, vT, attn);

    gemm_bf16<2><<<dim3(8, 32), 256, 0, stream>>>(attn, WgT, 1024, gate, bg, attn, nullptr, nullptr);
    gemm_bf16<3><<<dim3(8, 32), 256, 0, stream>>>(gate, WoT, 1024, nullptr, bo, nullptr, hidden, out);
}

// Round 7
// 346.294 us; speedup vs baseline: 1.1496x; 1.1496x over previous
//
#include <hip/hip_runtime.h>
#include <hip/hip_bf16.h>

typedef unsigned short u16;
typedef __bf16 bf16x8 __attribute__((ext_vector_type(8)));
typedef float f32x4 __attribute__((ext_vector_type(4)));

__device__ __forceinline__ u16 f2bf(float f) {
    union { float f; unsigned int u; } v; v.f = f;
    unsigned int u = v.u;
    unsigned int r = (u + 0x7fffu + ((u >> 16) & 1u)) >> 16;
    return (u16)r;
}
__device__ __forceinline__ float bf2f(u16 b) {
    union { unsigned int u; float f; } v; v.u = ((unsigned int)b) << 16;
    return v.f;
}

__device__ __forceinline__ void glds16(const u16* g, u16* l) {
    __builtin_amdgcn_global_load_lds(
        (__attribute__((address_space(1))) void*)(g),
        (__attribute__((address_space(3))) void*)(l), 16, 0, 0);
}

// ---------------- cast fp32 -> bf16 (vectorized) ----------------
__global__ __launch_bounds__(256) void cast_bf16_kernel(const float* __restrict__ src,
                                                        u16* __restrict__ dst, int n4) {
    int i = blockIdx.x * 256 + threadIdx.x;
    if (i >= n4) return;
    float4 v = ((const float4*)src)[i];
    ushort4 o;
    o.x = f2bf(v.x); o.y = f2bf(v.y); o.z = f2bf(v.z); o.w = f2bf(v.w);
    ((ushort4*)dst)[i] = o;
}

// ---------------- transpose+cast weights: WT[n][k] = W[k][n] ----------------
__global__ __launch_bounds__(256) void transpose_cast_kernel(
    const float* __restrict__ Wq, const float* __restrict__ Wk, const float* __restrict__ Wv,
    const float* __restrict__ Wg, const float* __restrict__ Wo,
    u16* __restrict__ WqT, u16* __restrict__ WkvT, u16* __restrict__ WgT, u16* __restrict__ WoT) {
    __shared__ float tile[32][33];
    const float* src; u16* dst;
    switch (blockIdx.z) {
        case 0: src = Wq; dst = WqT; break;
        case 1: src = Wk; dst = WkvT; break;
        case 2: src = Wv; dst = WkvT + (size_t)1024 * 1024; break;
        case 3: src = Wg; dst = WgT; break;
        default: src = Wo; dst = WoT; break;
    }
    int n0 = blockIdx.x * 32, k0 = blockIdx.y * 32;
    int tx = threadIdx.x, ty = threadIdx.y;   // (32, 8)
    #pragma unroll
    for (int j = 0; j < 4; j++)
        tile[ty + j * 8][tx] = src[(size_t)(k0 + ty + j * 8) * 1024 + n0 + tx];
    __syncthreads();
    #pragma unroll
    for (int j = 0; j < 4; j++)
        dst[(size_t)(n0 + ty + j * 8) * 1024 + k0 + tx] = f2bf(tile[tx][ty + j * 8]);
}

// ---------------- 128^2 bf16 MFMA GEMM (m97 structure) ----------------
template <int EPI>
__global__ __launch_bounds__(256) void gemm_bf16(
    const u16* __restrict__ A, const u16* __restrict__ B, int ldc,
    u16* __restrict__ Cbf, const float* __restrict__ bias,
    const u16* __restrict__ mul_src, const float* __restrict__ add_src,
    float* __restrict__ Cf) {
    constexpr int K = 1024;
    const int tid = threadIdx.x;
    const int w = tid >> 6, l = tid & 63;
    const int lr = l & 15, lg = l >> 4;
    const int wr = w >> 1, wc = w & 1;
    const int m0 = blockIdx.y * 128, n0 = blockIdx.x * 128;

    __shared__ u16 As[128 * 64];
    __shared__ u16 Bs[128 * 64];

    const f32x4 fz = {0.f, 0.f, 0.f, 0.f};
    f32x4 acc[4][4];
    #pragma unroll
    for (int i = 0; i < 4; i++)
        #pragma unroll
        for (int j = 0; j < 4; j++) acc[i][j] = fz;

    const int lane_row = l >> 3;
    const int lane_sl  = l & 7;
    const int src_ch   = lane_sl ^ lane_row;
    const u16* Ab = A + (size_t)(m0 + w * 32 + lane_row) * K + src_ch * 8;
    const u16* Bb = B + (size_t)(n0 + w * 32 + lane_row) * K + src_ch * 8;

    for (int kt = 0; kt < K; kt += 64) {
        __syncthreads();
        #pragma unroll
        for (int j = 0; j < 4; j++) {
            glds16(Ab + (size_t)j * 8 * K + kt, As + (w * 32 + j * 8) * 64);
            glds16(Bb + (size_t)j * 8 * K + kt, Bs + (w * 32 + j * 8) * 64);
        }
        __syncthreads();
        #pragma unroll
        for (int kk = 0; kk < 2; kk++) {
            bf16x8 af[4], bfr[4];
            #pragma unroll
            for (int mi = 0; mi < 4; mi++) {
                int row = wr * 64 + mi * 16 + lr;
                int ch = (kk * 4 + lg) ^ (row & 7);
                af[mi] = *(const bf16x8*)(As + row * 64 + ch * 8);
            }
            #pragma unroll
            for (int ni = 0; ni < 4; ni++) {
                int row = wc * 64 + ni * 16 + lr;
                int ch = (kk * 4 + lg) ^ (row & 7);
                bfr[ni] = *(const bf16x8*)(Bs + row * 64 + ch * 8);
            }
            #pragma unroll
            for (int mi = 0; mi < 4; mi++)
                #pragma unroll
                for (int ni = 0; ni < 4; ni++)
                    acc[mi][ni] = __builtin_amdgcn_mfma_f32_16x16x32_bf16(
                        af[mi], bfr[ni], acc[mi][ni], 0, 0, 0);
        }
    }

    #pragma unroll
    for (int mi = 0; mi < 4; mi++) {
        #pragma unroll
        for (int ni = 0; ni < 4; ni++) {
            #pragma unroll
            for (int r = 0; r < 4; r++) {
                int gm = m0 + wr * 64 + mi * 16 + lg * 4 + r;
                int gn = n0 + wc * 64 + ni * 16 + lr;
                float v = acc[mi][ni][r];
                if (EPI == 0) {
                    Cbf[(size_t)gm * ldc + gn] = f2bf(v);
                } else if (EPI == 2) {
                    float g = v + bias[gn];
                    float a = bf2f(mul_src[(size_t)gm * ldc + gn]);
                    float sg = 1.f / (1.f + __expf(-g));
                    Cbf[(size_t)gm * ldc + gn] = f2bf(a * sg);
                } else {
                    Cf[(size_t)gm * ldc + gn] = v + bias[gn] + add_src[(size_t)gm * ldc + gn];
                }
            }
        }
    }
}

// ---------------- hidden column-sum, stage 1: 16-row partials ----------------
__global__ __launch_bounds__(256) void hsum1_kernel(const float* __restrict__ hidden,
                                                    float* __restrict__ part) {
    int b = blockIdx.x, chunk = blockIdx.y;   // (2, 128)
    int tid = threadIdx.x;
    const float4* src = (const float4*)(hidden + ((size_t)b * 2048 + chunk * 16) * 1024) + tid;
    float4 acc = {0.f, 0.f, 0.f, 0.f};
    #pragma unroll
    for (int r = 0; r < 16; r++) {
        float4 v = src[r * 256];
        acc.x += v.x; acc.y += v.y; acc.z += v.z; acc.w += v.w;
    }
    ((float4*)(part + ((size_t)b * 128 + chunk) * 1024))[tid] = acc;
}

// ---------------- stage 2: reduce 128 partials -> mean ----------------
__global__ __launch_bounds__(256) void hsum2_kernel(const float* __restrict__ part,
                                                    float* __restrict__ hm) {
    int b = blockIdx.x, tid = threadIdx.x;
    const float4* src = (const float4*)(part + (size_t)b * 128 * 1024) + tid;
    float4 acc = {0.f, 0.f, 0.f, 0.f};
    for (int c = 0; c < 128; c++) {
        float4 v = src[c * 256];
        acc.x += v.x; acc.y += v.y; acc.z += v.z; acc.w += v.w;
    }
    const float inv = 1.f / 2048.f;
    acc.x *= inv; acc.y *= inv; acc.z *= inv; acc.w *= inv;
    ((float4*)(hm + (size_t)b * 1024))[tid] = acc;
}

// ---------------- qz: qsum = hmean @ Wq_h ; z = qsum @ Wk_h^T (per bh) ----------------
__global__ __launch_bounds__(256) void qz_kernel(const float* __restrict__ hm,
                                                 const u16* __restrict__ WqT,
                                                 const u16* __restrict__ WkT,
                                                 u16* __restrict__ z_bf) {
    int bh = blockIdx.x, b = bh >> 4, h = bh & 15;
    int tid = threadIdx.x;
    __shared__ float hm_l[1024];
    __shared__ float qs_l[64];
    __shared__ float red[256];
    ((float4*)hm_l)[tid] = ((const float4*)(hm + (size_t)b * 1024))[tid];
    __syncthreads();
    {
        int d = tid >> 2, q = tid & 3;
        const u16* wq = WqT + (size_t)(h * 64 + d) * 1024 + q * 256;
        float a = 0.f;
        for (int i = 0; i < 256; i += 8) {
            uint4 u = *(const uint4*)(wq + i);
            const u16* p = (const u16*)&u;
            #pragma unroll
            for (int j = 0; j < 8; j++) a += bf2f(p[j]) * hm_l[q * 256 + i + j];
        }
        red[tid] = a;
    }
    __syncthreads();
    if (tid < 64)
        qs_l[tid] = red[tid * 4] + red[tid * 4 + 1] + red[tid * 4 + 2] + red[tid * 4 + 3];
    __syncthreads();
    {
        float z0 = 0.f, z1 = 0.f, z2 = 0.f, z3 = 0.f;
        for (int d = 0; d < 64; d++) {
            float qs = qs_l[d];
            const u16* wk = WkT + (size_t)(h * 64 + d) * 1024 + tid * 4;
            uint2 u = *(const uint2*)wk;
            const u16* p = (const u16*)&u;
            z0 += qs * bf2f(p[0]); z1 += qs * bf2f(p[1]);
            z2 += qs * bf2f(p[2]); z3 += qs * bf2f(p[3]);
        }
        ushort4 o;
        o.x = f2bf(z0); o.y = f2bf(z1); o.z = f2bf(z2); o.w = f2bf(z3);
        *(ushort4*)(z_bf + (size_t)bh * 1024 + tid * 4) = o;
    }
}

// ---------------- score via MFMA: score[b*16+h][kv] = z[bh] . enc[kv] ----------------
__global__ __launch_bounds__(256) void score_mfma_kernel(const u16* __restrict__ ebf,
                                                         const u16* __restrict__ z_bf,
                                                         float* __restrict__ score) {
    const int b = blockIdx.y, kv0 = blockIdx.x * 256;
    const int tid = threadIdx.x, w = tid >> 6, l = tid & 63;
    const int lr = l & 15, lg = l >> 4;
    __shared__ u16 z_lds[16 * 1024];
    __shared__ u16 e_lds[256 * 64];
    {
        int row = tid >> 4, cg = tid & 15;
        const u16* src = z_bf + (size_t)(b * 16 + row) * 1024 + cg * 64;
        #pragma unroll
        for (int i = 0; i < 8; i++) {
            uint4 u = *(const uint4*)(src + i * 8);
            int ch = cg * 8 + i;
            *(uint4*)(z_lds + row * 1024 + (ch ^ (row & 7)) * 8) = u;
        }
    }
    const int lane_row = l >> 3, src_ch = (l & 7) ^ lane_row;
    const f32x4 fz = {0.f, 0.f, 0.f, 0.f};
    f32x4 acc[4];
    #pragma unroll
    for (int ni = 0; ni < 4; ni++) acc[ni] = fz;

    for (int kt = 0; kt < 1024; kt += 64) {
        __syncthreads();
        #pragma unroll
        for (int j = 0; j < 8; j++) {
            const u16* src = ebf + (size_t)(b * 16384 + kv0 + w * 64 + j * 8 + lane_row) * 1024 + kt + src_ch * 8;
            glds16(src, e_lds + (w * 64 + j * 8) * 64);
        }
        __syncthreads();
        #pragma unroll
        for (int ks = 0; ks < 2; ks++) {
            int chg = (kt >> 3) + ks * 4 + lg;
            bf16x8 af = *(const bf16x8*)(z_lds + lr * 1024 + (chg ^ (lr & 7)) * 8);
            #pragma unroll
            for (int ni = 0; ni < 4; ni++) {
                int row = w * 64 + ni * 16 + lr;
                bf16x8 bf_ = *(const bf16x8*)(e_lds + row * 64 + (((ks * 4 + lg) ^ (lr & 7))) * 8);
                acc[ni] = __builtin_amdgcn_mfma_f32_16x16x32_bf16(af, bf_, acc[ni], 0, 0, 0);
            }
        }
    }
    #pragma unroll
    for (int ni = 0; ni < 4; ni++)
        #pragma unroll
        for (int r = 0; r < 4; r++)
            score[(size_t)(b * 16 + lg * 4 + r) * 16384 + kv0 + w * 64 + ni * 16 + lr] = acc[ni][r];
}

// ---------------- radix top-2048 select per (b,h) ----------------
__global__ __launch_bounds__(256) void select_kernel(const float* __restrict__ score,
                                                     int* __restrict__ sel_idx) {
    int bh = blockIdx.x;
    const float* sc = score + (size_t)bh * 16384;
    __shared__ int hist[256];
    __shared__ int bc[4];
    int tid = threadIdx.x;
    if (tid == 0) { bc[0] = 0; bc[1] = 2048; bc[2] = 0; bc[3] = 0; }
    __syncthreads();
    for (int shift = 24; shift >= 0; shift -= 8) {
        hist[tid] = 0;
        __syncthreads();
        unsigned int prefix = (unsigned int)bc[0];
        unsigned int hi_mask = (shift == 24) ? 0u : (0xFFFFFFFFu << (shift + 8));
        for (int i = tid; i < 16384; i += 256) {
            unsigned int b = __float_as_uint(sc[i]);
            unsigned int ui = (b & 0x80000000u) ? ~b : (b | 0x80000000u);
            if ((ui & hi_mask) == (prefix & hi_mask))
                atomicAdd(&hist[(ui >> shift) & 0xff], 1);
        }
        __syncthreads();
        if (tid == 0) {
            int want = bc[1], acc = 0, d = 0;
            for (int dd = 255; dd >= 0; dd--) {
                acc += hist[dd];
                if (acc >= want) { d = dd; break; }
            }
            bc[1] = want - (acc - hist[d]);
            bc[0] = (int)(prefix | ((unsigned int)d << shift));
        }
        __syncthreads();
    }
    unsigned int uthr = (unsigned int)bc[0];
    int n_eq = bc[1];
    int base_eq = 2048 - n_eq;
    int* out = sel_idx + (size_t)bh * 2048;
    for (int i = tid; i < 16384; i += 256) {
        unsigned int b = __float_as_uint(sc[i]);
        unsigned int ui = (b & 0x80000000u) ? ~b : (b | 0x80000000u);
        if (ui > uthr) {
            int p = atomicAdd(&bc[2], 1);
            out[p] = i;
        } else if (ui == uthr) {
            int p = atomicAdd(&bc[3], 1);
            if (p < n_eq) out[base_eq + p] = i;
        }
    }
}

// ---------------- selected projection: K_sel[t][d] and V_selT[d][t] (chunk-swizzled) ----
__global__ __launch_bounds__(256) void selproj_kernel(const u16* __restrict__ ebf,
                                                      const u16* __restrict__ WkvT,
                                                      const int* __restrict__ sel_idx,
                                                      u16* __restrict__ k_sel,
                                                      u16* __restrict__ v_selT) {
    const int bh = blockIdx.y, b = bh >> 4, h = bh & 15;
    const int t0 = blockIdx.x * 128;
    const int tid = threadIdx.x, w = tid >> 6, l = tid & 63;
    const int lr = l & 15, lg = l >> 4;
    const int lane_row = l >> 3, src_ch = (l & 7) ^ lane_row;

    __shared__ u16 e_lds[128 * 64];
    __shared__ u16 w_lds[128 * 64];

    int encrow[4], wrow[4];
    #pragma unroll
    for (int j = 0; j < 4; j++) {
        int t = t0 + w * 32 + j * 8 + lane_row;
        encrow[j] = b * 16384 + sel_idx[(size_t)bh * 2048 + t];
        int r = w * 32 + j * 8 + lane_row;
        wrow[j] = (r < 64) ? (h * 64 + r) : (1024 + h * 64 + (r & 63));
    }

    const f32x4 fz = {0.f, 0.f, 0.f, 0.f};
    f32x4 acc_k[2][4], acc_v[8];
    #pragma unroll
    for (int i = 0; i < 2; i++)
        #pragma unroll
        for (int j = 0; j < 4; j++) acc_k[i][j] = fz;
    #pragma unroll
    for (int i = 0; i < 8; i++) acc_v[i] = fz;

    for (int kt = 0; kt < 1024; kt += 64) {
        __syncthreads();
        #pragma unroll
        for (int j = 0; j < 4; j++) {
            glds16(ebf + (size_t)encrow[j] * 1024 + kt + src_ch * 8, e_lds + (w * 32 + j * 8) * 64);
            glds16(WkvT + (size_t)wrow[j] * 1024 + kt + src_ch * 8, w_lds + (w * 32 + j * 8) * 64);
        }
        __syncthreads();
        #pragma unroll
        for (int ks = 0; ks < 2; ks++) {
            bf16x8 ae[2];
            #pragma unroll
            for (int mi = 0; mi < 2; mi++) {
                int row = w * 32 + mi * 16 + lr;
                ae[mi] = *(const bf16x8*)(e_lds + row * 64 + (((ks * 4 + lg) ^ (row & 7))) * 8);
            }
            bf16x8 aw;
            {
                int row = 64 + w * 16 + lr;
                aw = *(const bf16x8*)(w_lds + row * 64 + (((ks * 4 + lg) ^ (row & 7))) * 8);
            }
            #pragma unroll
            for (int ni = 0; ni < 4; ni++) {
                int row = ni * 16 + lr;
                bf16x8 bw = *(const bf16x8*)(w_lds + row * 64 + (((ks * 4 + lg) ^ (row & 7))) * 8);
                acc_k[0][ni] = __builtin_amdgcn_mfma_f32_16x16x32_bf16(ae[0], bw, acc_k[0][ni], 0, 0, 0);
                acc_k[1][ni] = __builtin_amdgcn_mfma_f32_16x16x32_bf16(ae[1], bw, acc_k[1][ni], 0, 0, 0);
            }
            #pragma unroll
            for (int ni = 0; ni < 8; ni++) {
                int row = ni * 16 + lr;
                bf16x8 be = *(const bf16x8*)(e_lds + row * 64 + (((ks * 4 + lg) ^ (row & 7))) * 8);
                acc_v[ni] = __builtin_amdgcn_mfma_f32_16x16x32_bf16(aw, be, acc_v[ni], 0, 0, 0);
            }
        }
    }

    u16* kb = k_sel + (size_t)bh * 2048 * 64;
    #pragma unroll
    for (int mi = 0; mi < 2; mi++)
        #pragma unroll
        for (int ni = 0; ni < 4; ni++)
            #pragma unroll
            for (int r = 0; r < 4; r++) {
                int t = t0 + w * 32 + mi * 16 + lg * 4 + r;
                int d = ni * 16 + lr;
                kb[(size_t)t * 64 + (((d >> 3) ^ (t & 7)) * 8) + (d & 7)] = f2bf(acc_k[mi][ni][r]);
            }
    u16* vb = v_selT + (size_t)bh * 64 * 2048;
    #pragma unroll
    for (int ni = 0; ni < 8; ni++)
        #pragma unroll
        for (int r = 0; r < 4; r++) {
            int d = w * 16 + lg * 4 + r;
            int t = t0 + ni * 16 + lr;
            int tl = t & 63;
            vb[(size_t)d * 2048 + (t & ~63) + ((((tl >> 3) ^ (d & 7))) * 8) + (tl & 7)] =
                f2bf(acc_v[ni][r]);
        }
}

// ---------------- flash attention: K dbuf prefetch, V single-buf mid-iter wait ----------------
__global__ __launch_bounds__(256) void attn_kernel(
    const u16* __restrict__ q_bf, const u16* __restrict__ k_sel,
    const u16* __restrict__ v_selT, u16* __restrict__ attn_out) {
    const int bh = blockIdx.y, b = bh >> 4, h = bh & 15;
    const int q0 = blockIdx.x * 64;
    const int tid = threadIdx.x, w = tid >> 6, l = tid & 63;
    const int lr = l & 15, lg = l >> 4;
    const int lk = lr & 7;
    const float SC = 0.18033688011f;   // 0.125 * log2(e)
    const float THR = 11.0f;

    __shared__ u16 k_lds[2][64 * 64];      // 16 KB (dbuf)
    __shared__ u16 vt_lds[64 * 64];        // 8 KB (single)
    __shared__ __bf16 p_lds[4][16][68];    // 8.7 KB, conflict-free stride
    // total 33.5 KB -> 4 blocks/CU

    const u16* qb = q_bf + ((size_t)b * 2048 + q0 + w * 16 + lr) * 1024 + h * 64;
    bf16x8 qf0 = *(const bf16x8*)(qb + lg * 8);
    bf16x8 qf1 = *(const bf16x8*)(qb + 32 + lg * 8);

    const f32x4 fz = {0.f, 0.f, 0.f, 0.f};
    f32x4 o[4];
    #pragma unroll
    for (int f = 0; f < 4; f++) o[f] = fz;
    float mm = -1e30f;                 // wave-uniform running max (log2 domain)
    float l_part[4] = {0.f, 0.f, 0.f, 0.f};   // per-lane partial l (reduced at end)

    const u16* kb  = k_sel + (size_t)bh * 2048 * 64;
    const u16* vtb = v_selT + (size_t)bh * 64 * 2048;

    auto stageK = [&](int it, int buf) {
        const u16* ksrc = kb + (size_t)(it * 64 + w * 16) * 64 + (size_t)l * 8;
        glds16(ksrc,       k_lds[buf] + (w * 16) * 64);
        glds16(ksrc + 512, k_lds[buf] + (w * 16 + 8) * 64);
    };
    auto stageV = [&](int it) {
        const u16* vsrc = vtb + (size_t)(w * 16 + (l >> 3)) * 2048 + it * 64 + (l & 7) * 8;
        glds16(vsrc,            vt_lds + (w * 16) * 64);
        glds16(vsrc + 8 * 2048, vt_lds + (w * 16 + 8) * 64);
    };

    stageK(0, 0);
    __syncthreads();   // drains K(0)

    #pragma unroll 1
    for (int it = 0; it < 32; ++it) {
        const int cur = it & 1;
        stageV(it);                                   // V for THIS tile (2 loads, oldest)
        if (it + 1 < 32) stageK(it + 1, cur ^ 1);     // K prefetch (2 loads, stay in flight)

        // QK^T on k_lds[cur]
        f32x4 s[4];
        #pragma unroll
        for (int c = 0; c < 4; c++) s[c] = fz;
        __builtin_amdgcn_s_setprio(1);
        #pragma unroll
        for (int c = 0; c < 4; c++) {
            const u16* krow = k_lds[cur] + (c * 16 + lr) * 64;
            bf16x8 kf0 = *(const bf16x8*)(krow + (lg ^ lk) * 8);
            s[c] = __builtin_amdgcn_mfma_f32_16x16x32_bf16(qf0, kf0, s[c], 0, 0, 0);
            bf16x8 kf1 = *(const bf16x8*)(krow + (((4 + lg) ^ lk)) * 8);
            s[c] = __builtin_amdgcn_mfma_f32_16x16x32_bf16(qf1, kf1, s[c], 0, 0, 0);
        }
        __builtin_amdgcn_s_setprio(0);

        // wave-uniform tile max (log2-scaled)
        float mx = s[0][0];
        #pragma unroll
        for (int c = 0; c < 4; c++)
            #pragma unroll
            for (int r = 0; r < 4; r++) mx = fmaxf(mx, s[c][r]);
        mx = fmaxf(mx, __shfl_xor(mx, 1));
        mx = fmaxf(mx, __shfl_xor(mx, 2));
        mx = fmaxf(mx, __shfl_xor(mx, 4));
        mx = fmaxf(mx, __shfl_xor(mx, 8));
        mx = fmaxf(mx, __shfl_xor(mx, 16));
        mx = fmaxf(mx, __shfl_xor(mx, 32));
        mx *= SC;
        if (mx > mm + THR) {                 // wave-uniform branch, fires rarely
            float al = __builtin_amdgcn_exp2f(mm - mx);
            mm = mx;
            #pragma unroll
            for (int r = 0; r < 4; r++) l_part[r] *= al;
            #pragma unroll
            for (int f = 0; f < 4; f++)
                #pragma unroll
                for (int r = 0; r < 4; r++) o[f][r] *= al;
        }
        // P = exp2(s*SC - mm); accumulate per-lane l; store bf16 to LDS
        #pragma unroll
        for (int c = 0; c < 4; c++) {
            #pragma unroll
            for (int r = 0; r < 4; r++) {
                float p = __builtin_amdgcn_exp2f(__builtin_fmaf(s[c][r], SC, -mm));
                l_part[r] += p;
                p_lds[w][lg * 4 + r][c * 16 + lr] = (__bf16)p;
            }
        }

        // wait for V (2 oldest loads), keep K prefetch in flight; then cross-wave barrier
        if (it + 1 < 32) {
            asm volatile("s_waitcnt vmcnt(2)" ::: "memory");
        } else {
            asm volatile("s_waitcnt vmcnt(0)" ::: "memory");
        }
        __builtin_amdgcn_sched_barrier(0);
        __builtin_amdgcn_s_barrier();

        // PV
        __builtin_amdgcn_s_setprio(1);
        #pragma unroll
        for (int kk = 0; kk < 2; kk++) {
            bf16x8 ap = *(const bf16x8*)(&p_lds[w][lr][kk * 32 + lg * 8]);
            #pragma unroll
            for (int f = 0; f < 4; f++) {
                const u16* vrow = vt_lds + (f * 16 + lr) * 64;
                bf16x8 bv = *(const bf16x8*)(vrow + (((kk * 4 + lg) ^ lk)) * 8);
                o[f] = __builtin_amdgcn_mfma_f32_16x16x32_bf16(ap, bv, o[f], 0, 0, 0);
            }
        }
        __builtin_amdgcn_s_setprio(0);

        __syncthreads();   // end-of-iter: all PV reads done; drains K prefetch
    }

    // final l reduction over the 16 k-lanes (lr), per r
    float invl[4];
    #pragma unroll
    for (int r = 0; r < 4; r++) {
        float lr_ = l_part[r];
        lr_ += __shfl_xor(lr_, 1);
        lr_ += __shfl_xor(lr_, 2);
        lr_ += __shfl_xor(lr_, 4);
        lr_ += __shfl_xor(lr_, 8);
        invl[r] = 1.f / lr_;
    }
    u16* ob = attn_out + ((size_t)b * 2048 + q0 + w * 16 + lg * 4) * 1024 + h * 64 + lr;
    #pragma unroll
    for (int f = 0; f < 4; f++) {
        #pragma unroll
        for (int r = 0; r < 4; r++) {
            __bf16 hv = (__bf16)(o[f][r] * invl[r]);
            ob[(size_t)r * 1024 + f * 16] = *(u16*)&hv;
        }
    }
}

// ---------------- launcher ----------------
extern "C" void kernel_launch(void* const* d_in, const int* in_sizes, int n_in,
                              void* d_out, int out_size, void* d_ws, size_t ws_size,
                              hipStream_t stream) {
    const float* hidden = (const float*)d_in[0];
    const float* enc    = (const float*)d_in[1];
    const float* Wq = (const float*)d_in[2];
    const float* Wk = (const float*)d_in[3];
    const float* Wv = (const float*)d_in[4];
    const float* Wo = (const float*)d_in[5];
    const float* bo = (const float*)d_in[6];
    const float* Wg = (const float*)d_in[7];
    const float* bg = (const float*)d_in[8];
    float* out = (float*)d_out;

    char* ws = (char*)d_ws;
    size_t off = 0;
    auto alloc = [&](size_t bytes) -> char* {
        char* p = ws + off;
        off += (bytes + 255) & ~(size_t)255;
        return p;
    };
    u16* hbf   = (u16*)alloc(4096ull * 1024 * 2);
    u16* ebf   = (u16*)alloc(32768ull * 1024 * 2);
    u16* WqT   = (u16*)alloc(1024ull * 1024 * 2);
    u16* WkvT  = (u16*)alloc(2048ull * 1024 * 2);
    u16* WgT   = (u16*)alloc(1024ull * 1024 * 2);
    u16* WoT   = (u16*)alloc(1024ull * 1024 * 2);
    u16* q_bf  = (u16*)alloc(4096ull * 1024 * 2);
    float* hm  = (float*)alloc(2ull * 1024 * 4);
    float* part = (float*)alloc(2ull * 128 * 1024 * 4);
    u16* z_bf  = (u16*)alloc(32ull * 1024 * 2);
    float* scor = (float*)alloc(32ull * 16384 * 4);
    int* sel    = (int*)alloc(32ull * 2048 * 4);
    u16* ksel   = (u16*)alloc(32ull * 2048 * 64 * 2);
    u16* vT     = (u16*)alloc(32ull * 64 * 2048 * 2);
    u16* attn   = (u16*)alloc(4096ull * 1024 * 2);
    u16* gate   = (u16*)alloc(4096ull * 1024 * 2);
    (void)ws_size; (void)in_sizes; (void)n_in; (void)out_size;

    hsum1_kernel<<<dim3(2, 128), 256, 0, stream>>>(hidden, part);
    hsum2_kernel<<<2, 256, 0, stream>>>(part, hm);
    cast_bf16_kernel<<<4096, 256, 0, stream>>>(hidden, hbf, 1048576);
    cast_bf16_kernel<<<32768, 256, 0, stream>>>(enc, ebf, 8388608);
    transpose_cast_kernel<<<dim3(32, 32, 5), dim3(32, 8), 0, stream>>>(
        Wq, Wk, Wv, Wg, Wo, WqT, WkvT, WgT, WoT);

    qz_kernel<<<32, 256, 0, stream>>>(hm, WqT, WkvT, z_bf);
    score_mfma_kernel<<<dim3(64, 2), 256, 0, stream>>>(ebf, z_bf, scor);
    select_kernel<<<32, 256, 0, stream>>>(scor, sel);
    selproj_kernel<<<dim3(16, 32), 256, 0, stream>>>(ebf, WkvT, sel, ksel, vT);

    gemm_bf16<0><<<dim3(8, 32), 256, 0, stream>>>(hbf, WqT, 1024, q_bf, nullptr, nullptr, nullptr, nullptr);
    attn_kernel<<<dim3(32, 32), 256, 0, stream>>>(q_bf, ksel, vT, attn);

    gemm_bf16<2><<<dim3(8, 32), 256, 0, stream>>>(attn, WgT, 1024, gate, bg, attn, nullptr, nullptr);
    gemm_bf16<3><<<dim3(8, 32), 256, 0, stream>>>(gate, WoT, 1024, nullptr, bo, nullptr, hidden, out);
}

// Round 8
// 275.438 us; speedup vs baseline: 1.4454x; 1.2572x over previous
//
#include <hip/hip_runtime.h>
#include <hip/hip_bf16.h>

typedef unsigned short u16;
typedef __bf16 bf16x8 __attribute__((ext_vector_type(8)));
typedef float f32x4 __attribute__((ext_vector_type(4)));

__device__ __forceinline__ u16 f2bf(float f) {
    union { float f; unsigned int u; } v; v.f = f;
    unsigned int u = v.u;
    unsigned int r = (u + 0x7fffu + ((u >> 16) & 1u)) >> 16;
    return (u16)r;
}
__device__ __forceinline__ float bf2f(u16 b) {
    union { unsigned int u; float f; } v; v.u = ((unsigned int)b) << 16;
    return v.f;
}

__device__ __forceinline__ void glds16(const u16* g, u16* l) {
    __builtin_amdgcn_global_load_lds(
        (__attribute__((address_space(1))) void*)(g),
        (__attribute__((address_space(3))) void*)(l), 16, 0, 0);
}

// ---------------- cast fp32 -> bf16 (vectorized) ----------------
__global__ __launch_bounds__(256) void cast_bf16_kernel(const float* __restrict__ src,
                                                        u16* __restrict__ dst, int n4) {
    int i = blockIdx.x * 256 + threadIdx.x;
    if (i >= n4) return;
    float4 v = ((const float4*)src)[i];
    ushort4 o;
    o.x = f2bf(v.x); o.y = f2bf(v.y); o.z = f2bf(v.z); o.w = f2bf(v.w);
    ((ushort4*)dst)[i] = o;
}

// ---------------- transpose+cast weights: WT[n][k] = W[k][n] ----------------
__global__ __launch_bounds__(256) void transpose_cast_kernel(
    const float* __restrict__ Wq, const float* __restrict__ Wk, const float* __restrict__ Wv,
    const float* __restrict__ Wg, const float* __restrict__ Wo,
    u16* __restrict__ WqT, u16* __restrict__ WkvT, u16* __restrict__ WgT, u16* __restrict__ WoT) {
    __shared__ float tile[32][33];
    const float* src; u16* dst;
    switch (blockIdx.z) {
        case 0: src = Wq; dst = WqT; break;
        case 1: src = Wk; dst = WkvT; break;
        case 2: src = Wv; dst = WkvT + (size_t)1024 * 1024; break;
        case 3: src = Wg; dst = WgT; break;
        default: src = Wo; dst = WoT; break;
    }
    int n0 = blockIdx.x * 32, k0 = blockIdx.y * 32;
    int tx = threadIdx.x, ty = threadIdx.y;   // (32, 8)
    #pragma unroll
    for (int j = 0; j < 4; j++)
        tile[ty + j * 8][tx] = src[(size_t)(k0 + ty + j * 8) * 1024 + n0 + tx];
    __syncthreads();
    #pragma unroll
    for (int j = 0; j < 4; j++)
        dst[(size_t)(n0 + ty + j * 8) * 1024 + k0 + tx] = f2bf(tile[tx][ty + j * 8]);
}

// ---------------- 128^2 bf16 MFMA GEMM (m97 structure) ----------------
template <int EPI>
__global__ __launch_bounds__(256) void gemm_bf16(
    const u16* __restrict__ A, const u16* __restrict__ B, int ldc,
    u16* __restrict__ Cbf, const float* __restrict__ bias,
    const u16* __restrict__ mul_src, const float* __restrict__ add_src,
    float* __restrict__ Cf) {
    constexpr int K = 1024;
    const int tid = threadIdx.x;
    const int w = tid >> 6, l = tid & 63;
    const int lr = l & 15, lg = l >> 4;
    const int wr = w >> 1, wc = w & 1;
    const int m0 = blockIdx.y * 128, n0 = blockIdx.x * 128;

    __shared__ u16 As[128 * 64];
    __shared__ u16 Bs[128 * 64];

    const f32x4 fz = {0.f, 0.f, 0.f, 0.f};
    f32x4 acc[4][4];
    #pragma unroll
    for (int i = 0; i < 4; i++)
        #pragma unroll
        for (int j = 0; j < 4; j++) acc[i][j] = fz;

    const int lane_row = l >> 3;
    const int lane_sl  = l & 7;
    const int src_ch   = lane_sl ^ lane_row;
    const u16* Ab = A + (size_t)(m0 + w * 32 + lane_row) * K + src_ch * 8;
    const u16* Bb = B + (size_t)(n0 + w * 32 + lane_row) * K + src_ch * 8;

    for (int kt = 0; kt < K; kt += 64) {
        __syncthreads();
        #pragma unroll
        for (int j = 0; j < 4; j++) {
            glds16(Ab + (size_t)j * 8 * K + kt, As + (w * 32 + j * 8) * 64);
            glds16(Bb + (size_t)j * 8 * K + kt, Bs + (w * 32 + j * 8) * 64);
        }
        __syncthreads();
        #pragma unroll
        for (int kk = 0; kk < 2; kk++) {
            bf16x8 af[4], bfr[4];
            #pragma unroll
            for (int mi = 0; mi < 4; mi++) {
                int row = wr * 64 + mi * 16 + lr;
                int ch = (kk * 4 + lg) ^ (row & 7);
                af[mi] = *(const bf16x8*)(As + row * 64 + ch * 8);
            }
            #pragma unroll
            for (int ni = 0; ni < 4; ni++) {
                int row = wc * 64 + ni * 16 + lr;
                int ch = (kk * 4 + lg) ^ (row & 7);
                bfr[ni] = *(const bf16x8*)(Bs + row * 64 + ch * 8);
            }
            #pragma unroll
            for (int mi = 0; mi < 4; mi++)
                #pragma unroll
                for (int ni = 0; ni < 4; ni++)
                    acc[mi][ni] = __builtin_amdgcn_mfma_f32_16x16x32_bf16(
                        af[mi], bfr[ni], acc[mi][ni], 0, 0, 0);
        }
    }

    #pragma unroll
    for (int mi = 0; mi < 4; mi++) {
        #pragma unroll
        for (int ni = 0; ni < 4; ni++) {
            #pragma unroll
            for (int r = 0; r < 4; r++) {
                int gm = m0 + wr * 64 + mi * 16 + lg * 4 + r;
                int gn = n0 + wc * 64 + ni * 16 + lr;
                float v = acc[mi][ni][r];
                if (EPI == 0) {
                    Cbf[(size_t)gm * ldc + gn] = f2bf(v);
                } else if (EPI == 2) {
                    float g = v + bias[gn];
                    float a = bf2f(mul_src[(size_t)gm * ldc + gn]);
                    float sg = 1.f / (1.f + __expf(-g));
                    Cbf[(size_t)gm * ldc + gn] = f2bf(a * sg);
                } else {
                    Cf[(size_t)gm * ldc + gn] = v + bias[gn] + add_src[(size_t)gm * ldc + gn];
                }
            }
        }
    }
}

// ---------------- hidden column-sum, stage 1: 16-row partials ----------------
__global__ __launch_bounds__(256) void hsum1_kernel(const float* __restrict__ hidden,
                                                    float* __restrict__ part) {
    int b = blockIdx.x, chunk = blockIdx.y;   // (2, 128)
    int tid = threadIdx.x;
    const float4* src = (const float4*)(hidden + ((size_t)b * 2048 + chunk * 16) * 1024) + tid;
    float4 acc = {0.f, 0.f, 0.f, 0.f};
    #pragma unroll
    for (int r = 0; r < 16; r++) {
        float4 v = src[r * 256];
        acc.x += v.x; acc.y += v.y; acc.z += v.z; acc.w += v.w;
    }
    ((float4*)(part + ((size_t)b * 128 + chunk) * 1024))[tid] = acc;
}

// ---------------- stage 2: reduce 128 partials -> mean ----------------
__global__ __launch_bounds__(256) void hsum2_kernel(const float* __restrict__ part,
                                                    float* __restrict__ hm) {
    int b = blockIdx.x, tid = threadIdx.x;
    const float4* src = (const float4*)(part + (size_t)b * 128 * 1024) + tid;
    float4 acc = {0.f, 0.f, 0.f, 0.f};
    for (int c = 0; c < 128; c++) {
        float4 v = src[c * 256];
        acc.x += v.x; acc.y += v.y; acc.z += v.z; acc.w += v.w;
    }
    const float inv = 1.f / 2048.f;
    acc.x *= inv; acc.y *= inv; acc.z *= inv; acc.w *= inv;
    ((float4*)(hm + (size_t)b * 1024))[tid] = acc;
}

// ---------------- qz: qsum = hmean @ Wq_h ; z = qsum @ Wk_h^T (per bh) ----------------
__global__ __launch_bounds__(256) void qz_kernel(const float* __restrict__ hm,
                                                 const u16* __restrict__ WqT,
                                                 const u16* __restrict__ WkT,
                                                 u16* __restrict__ z_bf) {
    int bh = blockIdx.x, b = bh >> 4, h = bh & 15;
    int tid = threadIdx.x;
    __shared__ float hm_l[1024];
    __shared__ float qs_l[64];
    __shared__ float red[256];
    ((float4*)hm_l)[tid] = ((const float4*)(hm + (size_t)b * 1024))[tid];
    __syncthreads();
    {
        int d = tid >> 2, q = tid & 3;
        const u16* wq = WqT + (size_t)(h * 64 + d) * 1024 + q * 256;
        float a = 0.f;
        for (int i = 0; i < 256; i += 8) {
            uint4 u = *(const uint4*)(wq + i);
            const u16* p = (const u16*)&u;
            #pragma unroll
            for (int j = 0; j < 8; j++) a += bf2f(p[j]) * hm_l[q * 256 + i + j];
        }
        red[tid] = a;
    }
    __syncthreads();
    if (tid < 64)
        qs_l[tid] = red[tid * 4] + red[tid * 4 + 1] + red[tid * 4 + 2] + red[tid * 4 + 3];
    __syncthreads();
    {
        float z0 = 0.f, z1 = 0.f, z2 = 0.f, z3 = 0.f;
        for (int d = 0; d < 64; d++) {
            float qs = qs_l[d];
            const u16* wk = WkT + (size_t)(h * 64 + d) * 1024 + tid * 4;
            uint2 u = *(const uint2*)wk;
            const u16* p = (const u16*)&u;
            z0 += qs * bf2f(p[0]); z1 += qs * bf2f(p[1]);
            z2 += qs * bf2f(p[2]); z3 += qs * bf2f(p[3]);
        }
        ushort4 o;
        o.x = f2bf(z0); o.y = f2bf(z1); o.z = f2bf(z2); o.w = f2bf(z3);
        *(ushort4*)(z_bf + (size_t)bh * 1024 + tid * 4) = o;
    }
}

// ---------------- score via MFMA: score[b*16+h][kv] = z[bh] . enc[kv] ----------------
__global__ __launch_bounds__(256) void score_mfma_kernel(const u16* __restrict__ ebf,
                                                         const u16* __restrict__ z_bf,
                                                         float* __restrict__ score) {
    const int b = blockIdx.y, kv0 = blockIdx.x * 256;
    const int tid = threadIdx.x, w = tid >> 6, l = tid & 63;
    const int lr = l & 15, lg = l >> 4;
    __shared__ u16 z_lds[16 * 1024];
    __shared__ u16 e_lds[256 * 64];
    {
        int row = tid >> 4, cg = tid & 15;
        const u16* src = z_bf + (size_t)(b * 16 + row) * 1024 + cg * 64;
        #pragma unroll
        for (int i = 0; i < 8; i++) {
            uint4 u = *(const uint4*)(src + i * 8);
            int ch = cg * 8 + i;
            *(uint4*)(z_lds + row * 1024 + (ch ^ (row & 7)) * 8) = u;
        }
    }
    const int lane_row = l >> 3, src_ch = (l & 7) ^ lane_row;
    const f32x4 fz = {0.f, 0.f, 0.f, 0.f};
    f32x4 acc[4];
    #pragma unroll
    for (int ni = 0; ni < 4; ni++) acc[ni] = fz;

    for (int kt = 0; kt < 1024; kt += 64) {
        __syncthreads();
        #pragma unroll
        for (int j = 0; j < 8; j++) {
            const u16* src = ebf + (size_t)(b * 16384 + kv0 + w * 64 + j * 8 + lane_row) * 1024 + kt + src_ch * 8;
            glds16(src, e_lds + (w * 64 + j * 8) * 64);
        }
        __syncthreads();
        #pragma unroll
        for (int ks = 0; ks < 2; ks++) {
            int chg = (kt >> 3) + ks * 4 + lg;
            bf16x8 af = *(const bf16x8*)(z_lds + lr * 1024 + (chg ^ (lr & 7)) * 8);
            #pragma unroll
            for (int ni = 0; ni < 4; ni++) {
                int row = w * 64 + ni * 16 + lr;
                bf16x8 bf_ = *(const bf16x8*)(e_lds + row * 64 + (((ks * 4 + lg) ^ (lr & 7))) * 8);
                acc[ni] = __builtin_amdgcn_mfma_f32_16x16x32_bf16(af, bf_, acc[ni], 0, 0, 0);
            }
        }
    }
    #pragma unroll
    for (int ni = 0; ni < 4; ni++)
        #pragma unroll
        for (int r = 0; r < 4; r++)
            score[(size_t)(b * 16 + lg * 4 + r) * 16384 + kv0 + w * 64 + ni * 16 + lr] = acc[ni][r];
}

// ---------------- top-2048 select: 16-bit keys, single sweep, 1024 threads ----------------
__global__ __launch_bounds__(1024) void select_kernel(const float* __restrict__ score,
                                                      int* __restrict__ sel_idx) {
    const int bh = blockIdx.x;
    const float* sc = score + (size_t)bh * 16384;
    const int tid = threadIdx.x;
    const int grp = tid >> 8;   // 4 histogram replicas

    __shared__ int hist[4][256];
    __shared__ int total[256];
    __shared__ int bc[4];   // thr, want, cnt_gt, cnt_eq

    // load all 16 keys into registers (one global sweep)
    u16 key[16];
    #pragma unroll
    for (int j = 0; j < 16; j++) {
        unsigned int b = __float_as_uint(sc[tid + j * 1024]);
        unsigned int ui = (b & 0x80000000u) ? ~b : (b | 0x80000000u);
        key[j] = (u16)(ui >> 16);
    }

    // pass 1: high byte
    ((int*)hist)[tid] = 0;
    __syncthreads();
    #pragma unroll
    for (int j = 0; j < 16; j++) atomicAdd(&hist[grp][key[j] >> 8], 1);
    __syncthreads();
    if (tid < 256) total[tid] = hist[0][tid] + hist[1][tid] + hist[2][tid] + hist[3][tid];
    __syncthreads();
    if (tid == 0) {
        int want = 2048, acc = 0;
        for (int dd = 255; dd >= 0; dd--) {
            acc += total[dd];
            if (acc >= want) { bc[0] = dd; bc[1] = want - (acc - total[dd]); break; }
        }
    }
    __syncthreads();
    const int hi = bc[0];
    const int want1 = bc[1];

    // pass 2: low byte among keys with high byte == hi
    ((int*)hist)[tid] = 0;
    __syncthreads();
    #pragma unroll
    for (int j = 0; j < 16; j++)
        if ((key[j] >> 8) == hi) atomicAdd(&hist[grp][key[j] & 0xff], 1);
    __syncthreads();
    if (tid < 256) total[tid] = hist[0][tid] + hist[1][tid] + hist[2][tid] + hist[3][tid];
    __syncthreads();
    if (tid == 0) {
        int want = want1, acc = 0;
        for (int dd = 255; dd >= 0; dd--) {
            acc += total[dd];
            if (acc >= want) { bc[0] = (hi << 8) | dd; bc[1] = want - (acc - total[dd]); break; }
        }
        bc[2] = 0; bc[3] = 0;
    }
    __syncthreads();
    const u16 thr = (u16)bc[0];
    const int n_eq = bc[1];
    const int base_eq = 2048 - n_eq;

    // emit from registers
    int* out = sel_idx + (size_t)bh * 2048;
    #pragma unroll
    for (int j = 0; j < 16; j++) {
        int i = tid + j * 1024;
        if (key[j] > thr) {
            int p = atomicAdd(&bc[2], 1);
            out[p] = i;
        } else if (key[j] == thr) {
            int p = atomicAdd(&bc[3], 1);
            if (p < n_eq) out[base_eq + p] = i;
        }
    }
}

// ---------------- selected projection: K_sel[t][d] and V_selT[d][t] (chunk-swizzled) ----
__global__ __launch_bounds__(256) void selproj_kernel(const u16* __restrict__ ebf,
                                                      const u16* __restrict__ WkvT,
                                                      const int* __restrict__ sel_idx,
                                                      u16* __restrict__ k_sel,
                                                      u16* __restrict__ v_selT) {
    const int bh = blockIdx.y, b = bh >> 4, h = bh & 15;
    const int t0 = blockIdx.x * 128;
    const int tid = threadIdx.x, w = tid >> 6, l = tid & 63;
    const int lr = l & 15, lg = l >> 4;
    const int lane_row = l >> 3, src_ch = (l & 7) ^ lane_row;

    __shared__ u16 e_lds[128 * 64];
    __shared__ u16 w_lds[128 * 64];

    int encrow[4], wrow[4];
    #pragma unroll
    for (int j = 0; j < 4; j++) {
        int t = t0 + w * 32 + j * 8 + lane_row;
        encrow[j] = b * 16384 + sel_idx[(size_t)bh * 2048 + t];
        int r = w * 32 + j * 8 + lane_row;
        wrow[j] = (r < 64) ? (h * 64 + r) : (1024 + h * 64 + (r & 63));
    }

    const f32x4 fz = {0.f, 0.f, 0.f, 0.f};
    f32x4 acc_k[2][4], acc_v[8];
    #pragma unroll
    for (int i = 0; i < 2; i++)
        #pragma unroll
        for (int j = 0; j < 4; j++) acc_k[i][j] = fz;
    #pragma unroll
    for (int i = 0; i < 8; i++) acc_v[i] = fz;

    for (int kt = 0; kt < 1024; kt += 64) {
        __syncthreads();
        #pragma unroll
        for (int j = 0; j < 4; j++) {
            glds16(ebf + (size_t)encrow[j] * 1024 + kt + src_ch * 8, e_lds + (w * 32 + j * 8) * 64);
            glds16(WkvT + (size_t)wrow[j] * 1024 + kt + src_ch * 8, w_lds + (w * 32 + j * 8) * 64);
        }
        __syncthreads();
        #pragma unroll
        for (int ks = 0; ks < 2; ks++) {
            bf16x8 ae[2];
            #pragma unroll
            for (int mi = 0; mi < 2; mi++) {
                int row = w * 32 + mi * 16 + lr;
                ae[mi] = *(const bf16x8*)(e_lds + row * 64 + (((ks * 4 + lg) ^ (row & 7))) * 8);
            }
            bf16x8 aw;
            {
                int row = 64 + w * 16 + lr;
                aw = *(const bf16x8*)(w_lds + row * 64 + (((ks * 4 + lg) ^ (row & 7))) * 8);
            }
            #pragma unroll
            for (int ni = 0; ni < 4; ni++) {
                int row = ni * 16 + lr;
                bf16x8 bw = *(const bf16x8*)(w_lds + row * 64 + (((ks * 4 + lg) ^ (row & 7))) * 8);
                acc_k[0][ni] = __builtin_amdgcn_mfma_f32_16x16x32_bf16(ae[0], bw, acc_k[0][ni], 0, 0, 0);
                acc_k[1][ni] = __builtin_amdgcn_mfma_f32_16x16x32_bf16(ae[1], bw, acc_k[1][ni], 0, 0, 0);
            }
            #pragma unroll
            for (int ni = 0; ni < 8; ni++) {
                int row = ni * 16 + lr;
                bf16x8 be = *(const bf16x8*)(e_lds + row * 64 + (((ks * 4 + lg) ^ (row & 7))) * 8);
                acc_v[ni] = __builtin_amdgcn_mfma_f32_16x16x32_bf16(aw, be, acc_v[ni], 0, 0, 0);
            }
        }
    }

    u16* kb = k_sel + (size_t)bh * 2048 * 64;
    #pragma unroll
    for (int mi = 0; mi < 2; mi++)
        #pragma unroll
        for (int ni = 0; ni < 4; ni++)
            #pragma unroll
            for (int r = 0; r < 4; r++) {
                int t = t0 + w * 32 + mi * 16 + lg * 4 + r;
                int d = ni * 16 + lr;
                kb[(size_t)t * 64 + (((d >> 3) ^ (t & 7)) * 8) + (d & 7)] = f2bf(acc_k[mi][ni][r]);
            }
    u16* vb = v_selT + (size_t)bh * 64 * 2048;
    #pragma unroll
    for (int ni = 0; ni < 8; ni++)
        #pragma unroll
        for (int r = 0; r < 4; r++) {
            int d = w * 16 + lg * 4 + r;
            int t = t0 + ni * 16 + lr;
            int tl = t & 63;
            vb[(size_t)d * 2048 + (t & ~63) + ((((tl >> 3) ^ (d & 7))) * 8) + (tl & 7)] =
                f2bf(acc_v[ni][r]);
        }
}

// ---------------- flash attention: K dbuf prefetch, V single-buf mid-iter wait ----------------
__global__ __launch_bounds__(256) void attn_kernel(
    const u16* __restrict__ q_bf, const u16* __restrict__ k_sel,
    const u16* __restrict__ v_selT, u16* __restrict__ attn_out) {
    const int bh = blockIdx.y, b = bh >> 4, h = bh & 15;
    const int q0 = blockIdx.x * 64;
    const int tid = threadIdx.x, w = tid >> 6, l = tid & 63;
    const int lr = l & 15, lg = l >> 4;
    const int lk = lr & 7;
    const float SC = 0.18033688011f;   // 0.125 * log2(e)
    const float THR = 11.0f;

    __shared__ u16 k_lds[2][64 * 64];
    __shared__ u16 vt_lds[64 * 64];
    __shared__ __bf16 p_lds[4][16][68];

    const u16* qb = q_bf + ((size_t)b * 2048 + q0 + w * 16 + lr) * 1024 + h * 64;
    bf16x8 qf0 = *(const bf16x8*)(qb + lg * 8);
    bf16x8 qf1 = *(const bf16x8*)(qb + 32 + lg * 8);

    const f32x4 fz = {0.f, 0.f, 0.f, 0.f};
    f32x4 o[4];
    #pragma unroll
    for (int f = 0; f < 4; f++) o[f] = fz;
    float mm = -1e30f;
    float l_part[4] = {0.f, 0.f, 0.f, 0.f};

    const u16* kb  = k_sel + (size_t)bh * 2048 * 64;
    const u16* vtb = v_selT + (size_t)bh * 64 * 2048;

    auto stageK = [&](int it, int buf) {
        const u16* ksrc = kb + (size_t)(it * 64 + w * 16) * 64 + (size_t)l * 8;
        glds16(ksrc,       k_lds[buf] + (w * 16) * 64);
        glds16(ksrc + 512, k_lds[buf] + (w * 16 + 8) * 64);
    };
    auto stageV = [&](int it) {
        const u16* vsrc = vtb + (size_t)(w * 16 + (l >> 3)) * 2048 + it * 64 + (l & 7) * 8;
        glds16(vsrc,            vt_lds + (w * 16) * 64);
        glds16(vsrc + 8 * 2048, vt_lds + (w * 16 + 8) * 64);
    };

    stageK(0, 0);
    __syncthreads();

    #pragma unroll 1
    for (int it = 0; it < 32; ++it) {
        const int cur = it & 1;
        stageV(it);
        if (it + 1 < 32) stageK(it + 1, cur ^ 1);

        f32x4 s[4];
        #pragma unroll
        for (int c = 0; c < 4; c++) s[c] = fz;
        __builtin_amdgcn_s_setprio(1);
        #pragma unroll
        for (int c = 0; c < 4; c++) {
            const u16* krow = k_lds[cur] + (c * 16 + lr) * 64;
            bf16x8 kf0 = *(const bf16x8*)(krow + (lg ^ lk) * 8);
            s[c] = __builtin_amdgcn_mfma_f32_16x16x32_bf16(qf0, kf0, s[c], 0, 0, 0);
            bf16x8 kf1 = *(const bf16x8*)(krow + (((4 + lg) ^ lk)) * 8);
            s[c] = __builtin_amdgcn_mfma_f32_16x16x32_bf16(qf1, kf1, s[c], 0, 0, 0);
        }
        __builtin_amdgcn_s_setprio(0);

        float mx = s[0][0];
        #pragma unroll
        for (int c = 0; c < 4; c++)
            #pragma unroll
            for (int r = 0; r < 4; r++) mx = fmaxf(mx, s[c][r]);
        mx = fmaxf(mx, __shfl_xor(mx, 1));
        mx = fmaxf(mx, __shfl_xor(mx, 2));
        mx = fmaxf(mx, __shfl_xor(mx, 4));
        mx = fmaxf(mx, __shfl_xor(mx, 8));
        mx = fmaxf(mx, __shfl_xor(mx, 16));
        mx = fmaxf(mx, __shfl_xor(mx, 32));
        mx *= SC;
        if (mx > mm + THR) {
            float al = __builtin_amdgcn_exp2f(mm - mx);
            mm = mx;
            #pragma unroll
            for (int r = 0; r < 4; r++) l_part[r] *= al;
            #pragma unroll
            for (int f = 0; f < 4; f++)
                #pragma unroll
                for (int r = 0; r < 4; r++) o[f][r] *= al;
        }
        #pragma unroll
        for (int c = 0; c < 4; c++) {
            #pragma unroll
            for (int r = 0; r < 4; r++) {
                float p = __builtin_amdgcn_exp2f(__builtin_fmaf(s[c][r], SC, -mm));
                l_part[r] += p;
                p_lds[w][lg * 4 + r][c * 16 + lr] = (__bf16)p;
            }
        }

        if (it + 1 < 32) {
            asm volatile("s_waitcnt vmcnt(2)" ::: "memory");
        } else {
            asm volatile("s_waitcnt vmcnt(0)" ::: "memory");
        }
        __builtin_amdgcn_sched_barrier(0);
        __builtin_amdgcn_s_barrier();

        __builtin_amdgcn_s_setprio(1);
        #pragma unroll
        for (int kk = 0; kk < 2; kk++) {
            bf16x8 ap = *(const bf16x8*)(&p_lds[w][lr][kk * 32 + lg * 8]);
            #pragma unroll
            for (int f = 0; f < 4; f++) {
                const u16* vrow = vt_lds + (f * 16 + lr) * 64;
                bf16x8 bv = *(const bf16x8*)(vrow + (((kk * 4 + lg) ^ lk)) * 8);
                o[f] = __builtin_amdgcn_mfma_f32_16x16x32_bf16(ap, bv, o[f], 0, 0, 0);
            }
        }
        __builtin_amdgcn_s_setprio(0);

        __syncthreads();
    }

    float invl[4];
    #pragma unroll
    for (int r = 0; r < 4; r++) {
        float lr_ = l_part[r];
        lr_ += __shfl_xor(lr_, 1);
        lr_ += __shfl_xor(lr_, 2);
        lr_ += __shfl_xor(lr_, 4);
        lr_ += __shfl_xor(lr_, 8);
        invl[r] = 1.f / lr_;
    }
    u16* ob = attn_out + ((size_t)b * 2048 + q0 + w * 16 + lg * 4) * 1024 + h * 64 + lr;
    #pragma unroll
    for (int f = 0; f < 4; f++) {
        #pragma unroll
        for (int r = 0; r < 4; r++) {
            __bf16 hv = (__bf16)(o[f][r] * invl[r]);
            ob[(size_t)r * 1024 + f * 16] = *(u16*)&hv;
        }
    }
}

// ---------------- launcher ----------------
extern "C" void kernel_launch(void* const* d_in, const int* in_sizes, int n_in,
                              void* d_out, int out_size, void* d_ws, size_t ws_size,
                              hipStream_t stream) {
    const float* hidden = (const float*)d_in[0];
    const float* enc    = (const float*)d_in[1];
    const float* Wq = (const float*)d_in[2];
    const float* Wk = (const float*)d_in[3];
    const float* Wv = (const float*)d_in[4];
    const float* Wo = (const float*)d_in[5];
    const float* bo = (const float*)d_in[6];
    const float* Wg = (const float*)d_in[7];
    const float* bg = (const float*)d_in[8];
    float* out = (float*)d_out;

    char* ws = (char*)d_ws;
    size_t off = 0;
    auto alloc = [&](size_t bytes) -> char* {
        char* p = ws + off;
        off += (bytes + 255) & ~(size_t)255;
        return p;
    };
    u16* hbf   = (u16*)alloc(4096ull * 1024 * 2);
    u16* ebf   = (u16*)alloc(32768ull * 1024 * 2);
    u16* WqT   = (u16*)alloc(1024ull * 1024 * 2);
    u16* WkvT  = (u16*)alloc(2048ull * 1024 * 2);
    u16* WgT   = (u16*)alloc(1024ull * 1024 * 2);
    u16* WoT   = (u16*)alloc(1024ull * 1024 * 2);
    u16* q_bf  = (u16*)alloc(4096ull * 1024 * 2);
    float* hm  = (float*)alloc(2ull * 1024 * 4);
    float* part = (float*)alloc(2ull * 128 * 1024 * 4);
    u16* z_bf  = (u16*)alloc(32ull * 1024 * 2);
    float* scor = (float*)alloc(32ull * 16384 * 4);
    int* sel    = (int*)alloc(32ull * 2048 * 4);
    u16* ksel   = (u16*)alloc(32ull * 2048 * 64 * 2);
    u16* vT     = (u16*)alloc(32ull * 64 * 2048 * 2);
    u16* attn   = (u16*)alloc(4096ull * 1024 * 2);
    u16* gate   = (u16*)alloc(4096ull * 1024 * 2);
    (void)ws_size; (void)in_sizes; (void)n_in; (void)out_size;

    hsum1_kernel<<<dim3(2, 128), 256, 0, stream>>>(hidden, part);
    hsum2_kernel<<<2, 256, 0, stream>>>(part, hm);
    cast_bf16_kernel<<<4096, 256, 0, stream>>>(hidden, hbf, 1048576);
    cast_bf16_kernel<<<32768, 256, 0, stream>>>(enc, ebf, 8388608);
    transpose_cast_kernel<<<dim3(32, 32, 5), dim3(32, 8), 0, stream>>>(
        Wq, Wk, Wv, Wg, Wo, WqT, WkvT, WgT, WoT);

    qz_kernel<<<32, 256, 0, stream>>>(hm, WqT, WkvT, z_bf);
    score_mfma_kernel<<<dim3(64, 2), 256, 0, stream>>>(ebf, z_bf, scor);
    select_kernel<<<32, 1024, 0, stream>>>(scor, sel);
    selproj_kernel<<<dim3(16, 32), 256, 0, stream>>>(ebf, WkvT, sel, ksel, vT);

    gemm_bf16<0><<<dim3(8, 32), 256, 0, stream>>>(hbf, WqT, 1024, q_bf, nullptr, nullptr, nullptr, nullptr);
    attn_kernel<<<dim3(32, 32), 256, 0, stream>>>(q_bf, ksel, vT, attn);

    gemm_bf16<2><<<dim3(8, 32), 256, 0, stream>>>(attn, WgT, 1024, gate, bg, attn, nullptr, nullptr);
    gemm_bf16<3><<<dim3(8, 32), 256, 0, stream>>>(gate, WoT, 1024, nullptr, bo, nullptr, hidden, out);
}

// Round 9
// 254.049 us; speedup vs baseline: 1.5671x; 1.0842x over previous
//
#include <hip/hip_runtime.h>
#include <hip/hip_bf16.h>

typedef unsigned short u16;
typedef __bf16 bf16x8 __attribute__((ext_vector_type(8)));
typedef float f32x4 __attribute__((ext_vector_type(4)));

__device__ __forceinline__ u16 f2bf(float f) {
    union { float f; unsigned int u; } v; v.f = f;
    unsigned int u = v.u;
    unsigned int r = (u + 0x7fffu + ((u >> 16) & 1u)) >> 16;
    return (u16)r;
}
__device__ __forceinline__ float bf2f(u16 b) {
    union { unsigned int u; float f; } v; v.u = ((unsigned int)b) << 16;
    return v.f;
}

__device__ __forceinline__ void glds16(const u16* g, u16* l) {
    __builtin_amdgcn_global_load_lds(
        (__attribute__((address_space(1))) void*)(g),
        (__attribute__((address_space(3))) void*)(l), 16, 0, 0);
}

// ---------------- cast fp32 -> bf16 (hidden only) ----------------
__global__ __launch_bounds__(256) void cast_bf16_kernel(const float* __restrict__ src,
                                                        u16* __restrict__ dst, int n4) {
    int i = blockIdx.x * 256 + threadIdx.x;
    if (i >= n4) return;
    float4 v = ((const float4*)src)[i];
    ushort4 o;
    o.x = f2bf(v.x); o.y = f2bf(v.y); o.z = f2bf(v.z); o.w = f2bf(v.w);
    ((ushort4*)dst)[i] = o;
}

// ---------------- transpose+cast weights: WT[n][k] = W[k][n] ----------------
__global__ __launch_bounds__(256) void transpose_cast_kernel(
    const float* __restrict__ Wq, const float* __restrict__ Wk, const float* __restrict__ Wv,
    const float* __restrict__ Wg, const float* __restrict__ Wo,
    u16* __restrict__ WqT, u16* __restrict__ WkvT, u16* __restrict__ WgT, u16* __restrict__ WoT) {
    __shared__ float tile[32][33];
    const float* src; u16* dst;
    switch (blockIdx.z) {
        case 0: src = Wq; dst = WqT; break;
        case 1: src = Wk; dst = WkvT; break;
        case 2: src = Wv; dst = WkvT + (size_t)1024 * 1024; break;
        case 3: src = Wg; dst = WgT; break;
        default: src = Wo; dst = WoT; break;
    }
    int n0 = blockIdx.x * 32, k0 = blockIdx.y * 32;
    int tx = threadIdx.x, ty = threadIdx.y;   // (32, 8)
    #pragma unroll
    for (int j = 0; j < 4; j++)
        tile[ty + j * 8][tx] = src[(size_t)(k0 + ty + j * 8) * 1024 + n0 + tx];
    __syncthreads();
    #pragma unroll
    for (int j = 0; j < 4; j++)
        dst[(size_t)(n0 + ty + j * 8) * 1024 + k0 + tx] = f2bf(tile[tx][ty + j * 8]);
}

// ---------------- 128^2 bf16 MFMA GEMM (m97 structure) ----------------
template <int EPI>
__global__ __launch_bounds__(256) void gemm_bf16(
    const u16* __restrict__ A, const u16* __restrict__ B, int ldc,
    u16* __restrict__ Cbf, const float* __restrict__ bias,
    const u16* __restrict__ mul_src, const float* __restrict__ add_src,
    float* __restrict__ Cf) {
    constexpr int K = 1024;
    const int tid = threadIdx.x;
    const int w = tid >> 6, l = tid & 63;
    const int lr = l & 15, lg = l >> 4;
    const int wr = w >> 1, wc = w & 1;
    const int m0 = blockIdx.y * 128, n0 = blockIdx.x * 128;

    __shared__ u16 As[128 * 64];
    __shared__ u16 Bs[128 * 64];

    const f32x4 fz = {0.f, 0.f, 0.f, 0.f};
    f32x4 acc[4][4];
    #pragma unroll
    for (int i = 0; i < 4; i++)
        #pragma unroll
        for (int j = 0; j < 4; j++) acc[i][j] = fz;

    const int lane_row = l >> 3;
    const int lane_sl  = l & 7;
    const int src_ch   = lane_sl ^ lane_row;
    const u16* Ab = A + (size_t)(m0 + w * 32 + lane_row) * K + src_ch * 8;
    const u16* Bb = B + (size_t)(n0 + w * 32 + lane_row) * K + src_ch * 8;

    for (int kt = 0; kt < K; kt += 64) {
        __syncthreads();
        #pragma unroll
        for (int j = 0; j < 4; j++) {
            glds16(Ab + (size_t)j * 8 * K + kt, As + (w * 32 + j * 8) * 64);
            glds16(Bb + (size_t)j * 8 * K + kt, Bs + (w * 32 + j * 8) * 64);
        }
        __syncthreads();
        #pragma unroll
        for (int kk = 0; kk < 2; kk++) {
            bf16x8 af[4], bfr[4];
            #pragma unroll
            for (int mi = 0; mi < 4; mi++) {
                int row = wr * 64 + mi * 16 + lr;
                int ch = (kk * 4 + lg) ^ (row & 7);
                af[mi] = *(const bf16x8*)(As + row * 64 + ch * 8);
            }
            #pragma unroll
            for (int ni = 0; ni < 4; ni++) {
                int row = wc * 64 + ni * 16 + lr;
                int ch = (kk * 4 + lg) ^ (row & 7);
                bfr[ni] = *(const bf16x8*)(Bs + row * 64 + ch * 8);
            }
            #pragma unroll
            for (int mi = 0; mi < 4; mi++)
                #pragma unroll
                for (int ni = 0; ni < 4; ni++)
                    acc[mi][ni] = __builtin_amdgcn_mfma_f32_16x16x32_bf16(
                        af[mi], bfr[ni], acc[mi][ni], 0, 0, 0);
        }
    }

    #pragma unroll
    for (int mi = 0; mi < 4; mi++) {
        #pragma unroll
        for (int ni = 0; ni < 4; ni++) {
            #pragma unroll
            for (int r = 0; r < 4; r++) {
                int gm = m0 + wr * 64 + mi * 16 + lg * 4 + r;
                int gn = n0 + wc * 64 + ni * 16 + lr;
                float v = acc[mi][ni][r];
                if (EPI == 0) {
                    Cbf[(size_t)gm * ldc + gn] = f2bf(v);
                } else if (EPI == 2) {
                    float g = v + bias[gn];
                    float a = bf2f(mul_src[(size_t)gm * ldc + gn]);
                    float sg = 1.f / (1.f + __expf(-g));
                    Cbf[(size_t)gm * ldc + gn] = f2bf(a * sg);
                } else {
                    Cf[(size_t)gm * ldc + gn] = v + bias[gn] + add_src[(size_t)gm * ldc + gn];
                }
            }
        }
    }
}

// ---------------- hidden column-sum, stage 1 ----------------
__global__ __launch_bounds__(256) void hsum1_kernel(const float* __restrict__ hidden,
                                                    float* __restrict__ part) {
    int b = blockIdx.x, chunk = blockIdx.y;   // (2, 128)
    int tid = threadIdx.x;
    const float4* src = (const float4*)(hidden + ((size_t)b * 2048 + chunk * 16) * 1024) + tid;
    float4 acc = {0.f, 0.f, 0.f, 0.f};
    #pragma unroll
    for (int r = 0; r < 16; r++) {
        float4 v = src[r * 256];
        acc.x += v.x; acc.y += v.y; acc.z += v.z; acc.w += v.w;
    }
    ((float4*)(part + ((size_t)b * 128 + chunk) * 1024))[tid] = acc;
}

// ---------------- stage 2: mean ----------------
__global__ __launch_bounds__(256) void hsum2_kernel(const float* __restrict__ part,
                                                    float* __restrict__ hm) {
    int b = blockIdx.x, tid = threadIdx.x;
    const float4* src = (const float4*)(part + (size_t)b * 128 * 1024) + tid;
    float4 acc = {0.f, 0.f, 0.f, 0.f};
    for (int c = 0; c < 128; c++) {
        float4 v = src[c * 256];
        acc.x += v.x; acc.y += v.y; acc.z += v.z; acc.w += v.w;
    }
    const float inv = 1.f / 2048.f;
    acc.x *= inv; acc.y *= inv; acc.z *= inv; acc.w *= inv;
    ((float4*)(hm + (size_t)b * 1024))[tid] = acc;
}

// ---------------- qz ----------------
__global__ __launch_bounds__(256) void qz_kernel(const float* __restrict__ hm,
                                                 const u16* __restrict__ WqT,
                                                 const u16* __restrict__ WkT,
                                                 u16* __restrict__ z_bf) {
    int bh = blockIdx.x, b = bh >> 4, h = bh & 15;
    int tid = threadIdx.x;
    __shared__ float hm_l[1024];
    __shared__ float qs_l[64];
    __shared__ float red[256];
    ((float4*)hm_l)[tid] = ((const float4*)(hm + (size_t)b * 1024))[tid];
    __syncthreads();
    {
        int d = tid >> 2, q = tid & 3;
        const u16* wq = WqT + (size_t)(h * 64 + d) * 1024 + q * 256;
        float a = 0.f;
        for (int i = 0; i < 256; i += 8) {
            uint4 u = *(const uint4*)(wq + i);
            const u16* p = (const u16*)&u;
            #pragma unroll
            for (int j = 0; j < 8; j++) a += bf2f(p[j]) * hm_l[q * 256 + i + j];
        }
        red[tid] = a;
    }
    __syncthreads();
    if (tid < 64)
        qs_l[tid] = red[tid * 4] + red[tid * 4 + 1] + red[tid * 4 + 2] + red[tid * 4 + 3];
    __syncthreads();
    {
        float z0 = 0.f, z1 = 0.f, z2 = 0.f, z3 = 0.f;
        for (int d = 0; d < 64; d++) {
            float qs = qs_l[d];
            const u16* wk = WkT + (size_t)(h * 64 + d) * 1024 + tid * 4;
            uint2 u = *(const uint2*)wk;
            const u16* p = (const u16*)&u;
            z0 += qs * bf2f(p[0]); z1 += qs * bf2f(p[1]);
            z2 += qs * bf2f(p[2]); z3 += qs * bf2f(p[3]);
        }
        ushort4 o;
        o.x = f2bf(z0); o.y = f2bf(z1); o.z = f2bf(z2); o.w = f2bf(z3);
        *(ushort4*)(z_bf + (size_t)bh * 1024 + tid * 4) = o;
    }
}

// ---------------- escore: fused enc cast + selection score (MFMA) ----------------
// Per block: 128 kv rows. Reads fp32 enc, writes bf16 ebf, computes score.
__global__ __launch_bounds__(256) void escore_kernel(const float* __restrict__ enc,
                                                     const u16* __restrict__ z_bf,
                                                     u16* __restrict__ ebf,
                                                     float* __restrict__ score) {
    const int b = blockIdx.y, kv0 = blockIdx.x * 128;
    const int tid = threadIdx.x, w = tid >> 6, l = tid & 63;
    const int lr = l & 15, lg = l >> 4;
    __shared__ u16 z_lds[16 * 1024];   // 32 KB
    __shared__ u16 e_lds[128 * 64];    // 16 KB
    {   // stage all 16 heads' z, chunk-swizzled
        int row = tid >> 4, cg = tid & 15;
        const u16* src = z_bf + (size_t)(b * 16 + row) * 1024 + cg * 64;
        #pragma unroll
        for (int i = 0; i < 8; i++) {
            uint4 u = *(const uint4*)(src + i * 8);
            int ch = cg * 8 + i;
            *(uint4*)(z_lds + row * 1024 + (ch ^ (row & 7)) * 8) = u;
        }
    }
    const int rbase = tid >> 4;          // 0..15
    const int cgrp  = tid & 15;          // column group (4 floats)
    const float* ebase = enc + (size_t)(b * 16384 + kv0) * 1024;
    u16* obase = ebf + (size_t)(b * 16384 + kv0) * 1024;

    float4 rv[8];
    auto loadT = [&](int kt) {
        #pragma unroll
        for (int jj = 0; jj < 8; jj++) {
            int row = rbase + jj * 16;
            rv[jj] = *(const float4*)(ebase + (size_t)row * 1024 + kt + cgrp * 4);
        }
    };
    loadT(0);

    const f32x4 fz = {0.f, 0.f, 0.f, 0.f};
    f32x4 acc[2];
    acc[0] = fz; acc[1] = fz;
    __syncthreads();   // z_lds ready

    for (int kt = 0; kt < 1024; kt += 64) {
        // cvt + LDS(swizzled) + global write
        #pragma unroll
        for (int jj = 0; jj < 8; jj++) {
            int row = rbase + jj * 16;
            ushort4 pk;
            pk.x = f2bf(rv[jj].x); pk.y = f2bf(rv[jj].y);
            pk.z = f2bf(rv[jj].z); pk.w = f2bf(rv[jj].w);
            int ch = cgrp >> 1;
            int off = ((ch ^ (row & 7)) * 8) + ((cgrp & 1) * 4);
            *(ushort4*)(e_lds + row * 64 + off) = pk;
            *(ushort4*)(obase + (size_t)row * 1024 + kt + cgrp * 4) = pk;
        }
        __syncthreads();   // e_lds ready
        if (kt + 64 < 1024) loadT(kt + 64);
        #pragma unroll
        for (int ks = 0; ks < 2; ks++) {
            int chg = (kt >> 3) + ks * 4 + lg;
            bf16x8 af = *(const bf16x8*)(z_lds + lr * 1024 + (chg ^ (lr & 7)) * 8);
            #pragma unroll
            for (int ni = 0; ni < 2; ni++) {
                int row = w * 32 + ni * 16 + lr;
                bf16x8 bf_ = *(const bf16x8*)(e_lds + row * 64 + (((ks * 4 + lg) ^ (lr & 7))) * 8);
                acc[ni] = __builtin_amdgcn_mfma_f32_16x16x32_bf16(af, bf_, acc[ni], 0, 0, 0);
            }
        }
        __syncthreads();   // before e_lds overwrite
    }
    #pragma unroll
    for (int ni = 0; ni < 2; ni++)
        #pragma unroll
        for (int r = 0; r < 4; r++)
            score[(size_t)(b * 16 + lg * 4 + r) * 16384 + kv0 + w * 32 + ni * 16 + lr] = acc[ni][r];
}

// ---------------- top-2048 select: 16-bit keys, single sweep, 1024 threads ----------------
__global__ __launch_bounds__(1024) void select_kernel(const float* __restrict__ score,
                                                      int* __restrict__ sel_idx) {
    const int bh = blockIdx.x;
    const float* sc = score + (size_t)bh * 16384;
    const int tid = threadIdx.x;
    const int grp = tid >> 8;

    __shared__ int hist[4][256];
    __shared__ int total[256];
    __shared__ int bc[4];

    u16 key[16];
    #pragma unroll
    for (int j = 0; j < 16; j++) {
        unsigned int b = __float_as_uint(sc[tid + j * 1024]);
        unsigned int ui = (b & 0x80000000u) ? ~b : (b | 0x80000000u);
        key[j] = (u16)(ui >> 16);
    }

    ((int*)hist)[tid] = 0;
    __syncthreads();
    #pragma unroll
    for (int j = 0; j < 16; j++) atomicAdd(&hist[grp][key[j] >> 8], 1);
    __syncthreads();
    if (tid < 256) total[tid] = hist[0][tid] + hist[1][tid] + hist[2][tid] + hist[3][tid];
    __syncthreads();
    if (tid == 0) {
        int want = 2048, acc = 0;
        for (int dd = 255; dd >= 0; dd--) {
            acc += total[dd];
            if (acc >= want) { bc[0] = dd; bc[1] = want - (acc - total[dd]); break; }
        }
    }
    __syncthreads();
    const int hi = bc[0];
    const int want1 = bc[1];

    ((int*)hist)[tid] = 0;
    __syncthreads();
    #pragma unroll
    for (int j = 0; j < 16; j++)
        if ((key[j] >> 8) == hi) atomicAdd(&hist[grp][key[j] & 0xff], 1);
    __syncthreads();
    if (tid < 256) total[tid] = hist[0][tid] + hist[1][tid] + hist[2][tid] + hist[3][tid];
    __syncthreads();
    if (tid == 0) {
        int want = want1, acc = 0;
        for (int dd = 255; dd >= 0; dd--) {
            acc += total[dd];
            if (acc >= want) { bc[0] = (hi << 8) | dd; bc[1] = want - (acc - total[dd]); break; }
        }
        bc[2] = 0; bc[3] = 0;
    }
    __syncthreads();
    const u16 thr = (u16)bc[0];
    const int n_eq = bc[1];
    const int base_eq = 2048 - n_eq;

    int* out = sel_idx + (size_t)bh * 2048;
    #pragma unroll
    for (int j = 0; j < 16; j++) {
        int i = tid + j * 1024;
        if (key[j] > thr) {
            int p = atomicAdd(&bc[2], 1);
            out[p] = i;
        } else if (key[j] == thr) {
            int p = atomicAdd(&bc[3], 1);
            if (p < n_eq) out[base_eq + p] = i;
        }
    }
}

// ---------------- selected projection: K_sel (chunk-swz) + V_selT (kappa-permuted, chunk-swz) ----
__global__ __launch_bounds__(256) void selproj_kernel(const u16* __restrict__ ebf,
                                                      const u16* __restrict__ WkvT,
                                                      const int* __restrict__ sel_idx,
                                                      u16* __restrict__ k_sel,
                                                      u16* __restrict__ v_selT) {
    const int bh = blockIdx.y, b = bh >> 4, h = bh & 15;
    const int t0 = blockIdx.x * 128;
    const int tid = threadIdx.x, w = tid >> 6, l = tid & 63;
    const int lr = l & 15, lg = l >> 4;
    const int lane_row = l >> 3, src_ch = (l & 7) ^ lane_row;

    __shared__ u16 e_lds[128 * 64];
    __shared__ u16 w_lds[128 * 64];

    int encrow[4], wrow[4];
    #pragma unroll
    for (int j = 0; j < 4; j++) {
        int t = t0 + w * 32 + j * 8 + lane_row;
        encrow[j] = b * 16384 + sel_idx[(size_t)bh * 2048 + t];
        int r = w * 32 + j * 8 + lane_row;
        wrow[j] = (r < 64) ? (h * 64 + r) : (1024 + h * 64 + (r & 63));
    }

    const f32x4 fz = {0.f, 0.f, 0.f, 0.f};
    f32x4 acc_k[2][4], acc_v[8];
    #pragma unroll
    for (int i = 0; i < 2; i++)
        #pragma unroll
        for (int j = 0; j < 4; j++) acc_k[i][j] = fz;
    #pragma unroll
    for (int i = 0; i < 8; i++) acc_v[i] = fz;

    for (int kt = 0; kt < 1024; kt += 64) {
        __syncthreads();
        #pragma unroll
        for (int j = 0; j < 4; j++) {
            glds16(ebf + (size_t)encrow[j] * 1024 + kt + src_ch * 8, e_lds + (w * 32 + j * 8) * 64);
            glds16(WkvT + (size_t)wrow[j] * 1024 + kt + src_ch * 8, w_lds + (w * 32 + j * 8) * 64);
        }
        __syncthreads();
        #pragma unroll
        for (int ks = 0; ks < 2; ks++) {
            bf16x8 ae[2];
            #pragma unroll
            for (int mi = 0; mi < 2; mi++) {
                int row = w * 32 + mi * 16 + lr;
                ae[mi] = *(const bf16x8*)(e_lds + row * 64 + (((ks * 4 + lg) ^ (row & 7))) * 8);
            }
            bf16x8 aw;
            {
                int row = 64 + w * 16 + lr;
                aw = *(const bf16x8*)(w_lds + row * 64 + (((ks * 4 + lg) ^ (row & 7))) * 8);
            }
            #pragma unroll
            for (int ni = 0; ni < 4; ni++) {
                int row = ni * 16 + lr;
                bf16x8 bw = *(const bf16x8*)(w_lds + row * 64 + (((ks * 4 + lg) ^ (row & 7))) * 8);
                acc_k[0][ni] = __builtin_amdgcn_mfma_f32_16x16x32_bf16(ae[0], bw, acc_k[0][ni], 0, 0, 0);
                acc_k[1][ni] = __builtin_amdgcn_mfma_f32_16x16x32_bf16(ae[1], bw, acc_k[1][ni], 0, 0, 0);
            }
            #pragma unroll
            for (int ni = 0; ni < 8; ni++) {
                int row = ni * 16 + lr;
                bf16x8 be = *(const bf16x8*)(e_lds + row * 64 + (((ks * 4 + lg) ^ (row & 7))) * 8);
                acc_v[ni] = __builtin_amdgcn_mfma_f32_16x16x32_bf16(aw, be, acc_v[ni], 0, 0, 0);
            }
        }
    }

    u16* kb = k_sel + (size_t)bh * 2048 * 64;
    #pragma unroll
    for (int mi = 0; mi < 2; mi++)
        #pragma unroll
        for (int ni = 0; ni < 4; ni++)
            #pragma unroll
            for (int r = 0; r < 4; r++) {
                int t = t0 + w * 32 + mi * 16 + lg * 4 + r;
                int d = ni * 16 + lr;
                kb[(size_t)t * 64 + (((d >> 3) ^ (t & 7)) * 8) + (d & 7)] = f2bf(acc_k[mi][ni][r]);
            }
    // V epilogue: kappa-permuted columns (kappa = (tl&15)*4 + (tl>>4)), chunk-swizzled by d&7
    u16* vb = v_selT + (size_t)bh * 64 * 2048;
    #pragma unroll
    for (int ni = 0; ni < 8; ni++)
        #pragma unroll
        for (int r = 0; r < 4; r++) {
            int d = w * 16 + lg * 4 + r;
            int t = t0 + ni * 16 + lr;
            int tl = t & 63;
            int kap = (tl & 15) * 4 + (tl >> 4);
            vb[(size_t)d * 2048 + (t & ~63) + (((kap >> 3) ^ (d & 7)) * 8) + (kap & 7)] =
                f2bf(acc_v[ni][r]);
        }
}

// ---------------- flash attention: 8 waves, QBLK=128, kappa-packed P store ----------------
__global__ __launch_bounds__(512) void attn_kernel(
    const u16* __restrict__ q_bf, const u16* __restrict__ k_sel,
    const u16* __restrict__ v_selT, u16* __restrict__ attn_out) {
    const int bh = blockIdx.y, b = bh >> 4, h = bh & 15;
    const int q0 = blockIdx.x * 128;
    const int tid = threadIdx.x, w = tid >> 6, l = tid & 63;
    const int lr = l & 15, lg = l >> 4;
    const int lk = lr & 7;
    const float SC = 0.18033688011f;   // 0.125 * log2(e)
    const float THR = 11.0f;

    __shared__ u16 k_lds[2][64 * 64];     // 16 KB dbuf
    __shared__ u16 vt_lds[64 * 64];       // 8 KB single
    __shared__ u16 p_lds[8][16][68];      // 17.4 KB, b64 writes ~2-way max

    const u16* qb = q_bf + ((size_t)b * 2048 + q0 + w * 16 + lr) * 1024 + h * 64;
    bf16x8 qf0 = *(const bf16x8*)(qb + lg * 8);
    bf16x8 qf1 = *(const bf16x8*)(qb + 32 + lg * 8);

    const f32x4 fz = {0.f, 0.f, 0.f, 0.f};
    f32x4 o[4];
    #pragma unroll
    for (int f = 0; f < 4; f++) o[f] = fz;
    float mm = -1e30f;
    float l_part[4] = {0.f, 0.f, 0.f, 0.f};

    const u16* kb  = k_sel + (size_t)bh * 2048 * 64;
    const u16* vtb = v_selT + (size_t)bh * 64 * 2048;

    // 512 threads: each wave stages 8 rows of the 64x64 tile with ONE glds16
    auto stageK = [&](int it, int buf) {
        const u16* ksrc = kb + (size_t)(it * 64 + w * 8) * 64 + (size_t)l * 8;
        glds16(ksrc, k_lds[buf] + (w * 8) * 64);
    };
    auto stageV = [&](int it) {
        const u16* vsrc = vtb + (size_t)(w * 8 + (l >> 3)) * 2048 + it * 64 + (l & 7) * 8;
        glds16(vsrc, vt_lds + (w * 8) * 64);
    };

    stageK(0, 0);
    __syncthreads();

    #pragma unroll 1
    for (int it = 0; it < 32; ++it) {
        const int cur = it & 1;
        stageV(it);                                 // 1 load (oldest)
        if (it + 1 < 32) stageK(it + 1, cur ^ 1);   // 1 load (stays in flight)

        // QK^T
        f32x4 s[4];
        #pragma unroll
        for (int c = 0; c < 4; c++) s[c] = fz;
        __builtin_amdgcn_s_setprio(1);
        #pragma unroll
        for (int c = 0; c < 4; c++) {
            const u16* krow = k_lds[cur] + (c * 16 + lr) * 64;
            bf16x8 kf0 = *(const bf16x8*)(krow + (lg ^ lk) * 8);
            s[c] = __builtin_amdgcn_mfma_f32_16x16x32_bf16(qf0, kf0, s[c], 0, 0, 0);
            bf16x8 kf1 = *(const bf16x8*)(krow + (((4 + lg) ^ lk)) * 8);
            s[c] = __builtin_amdgcn_mfma_f32_16x16x32_bf16(qf1, kf1, s[c], 0, 0, 0);
        }
        __builtin_amdgcn_s_setprio(0);

        // wave-uniform tile max
        float mx = s[0][0];
        #pragma unroll
        for (int c = 0; c < 4; c++)
            #pragma unroll
            for (int r = 0; r < 4; r++) mx = fmaxf(mx, s[c][r]);
        mx = fmaxf(mx, __shfl_xor(mx, 1));
        mx = fmaxf(mx, __shfl_xor(mx, 2));
        mx = fmaxf(mx, __shfl_xor(mx, 4));
        mx = fmaxf(mx, __shfl_xor(mx, 8));
        mx = fmaxf(mx, __shfl_xor(mx, 16));
        mx = fmaxf(mx, __shfl_xor(mx, 32));
        mx *= SC;
        if (mx > mm + THR) {
            float al = __builtin_amdgcn_exp2f(mm - mx);
            mm = mx;
            #pragma unroll
            for (int r = 0; r < 4; r++) l_part[r] *= al;
            #pragma unroll
            for (int f = 0; f < 4; f++)
                #pragma unroll
                for (int r = 0; r < 4; r++) o[f][r] *= al;
        }
        // P = exp2(s*SC - mm); kappa-packed b64 store: P[q=lg*4+r][kappa=lr*4+c]
        #pragma unroll
        for (int r = 0; r < 4; r++) {
            ushort4 pk;
            u16 pb[4];
            #pragma unroll
            for (int c = 0; c < 4; c++) {
                float p = __builtin_amdgcn_exp2f(__builtin_fmaf(s[c][r], SC, -mm));
                l_part[r] += p;
                __bf16 hv = (__bf16)p;
                pb[c] = *(u16*)&hv;
            }
            pk.x = pb[0]; pk.y = pb[1]; pk.z = pb[2]; pk.w = pb[3];
            *(ushort4*)(&p_lds[w][lg * 4 + r][lr * 4]) = pk;
        }

        // wait V (oldest), keep K prefetch in flight; then cross-wave barrier
        if (it + 1 < 32) {
            asm volatile("s_waitcnt vmcnt(1)" ::: "memory");
        } else {
            asm volatile("s_waitcnt vmcnt(0)" ::: "memory");
        }
        __builtin_amdgcn_sched_barrier(0);
        __builtin_amdgcn_s_barrier();

        // PV: A = P (kappa order), B = V^T (kappa-permuted storage)
        __builtin_amdgcn_s_setprio(1);
        #pragma unroll
        for (int kk = 0; kk < 2; kk++) {
            bf16x8 ap = *(const bf16x8*)(&p_lds[w][lr][kk * 32 + lg * 8]);
            #pragma unroll
            for (int f = 0; f < 4; f++) {
                const u16* vrow = vt_lds + (f * 16 + lr) * 64;
                bf16x8 bv = *(const bf16x8*)(vrow + (((kk * 4 + lg) ^ lk)) * 8);
                o[f] = __builtin_amdgcn_mfma_f32_16x16x32_bf16(ap, bv, o[f], 0, 0, 0);
            }
        }
        __builtin_amdgcn_s_setprio(0);

        __syncthreads();
    }

    float invl[4];
    #pragma unroll
    for (int r = 0; r < 4; r++) {
        float lr_ = l_part[r];
        lr_ += __shfl_xor(lr_, 1);
        lr_ += __shfl_xor(lr_, 2);
        lr_ += __shfl_xor(lr_, 4);
        lr_ += __shfl_xor(lr_, 8);
        invl[r] = 1.f / lr_;
    }
    u16* ob = attn_out + ((size_t)b * 2048 + q0 + w * 16 + lg * 4) * 1024 + h * 64 + lr;
    #pragma unroll
    for (int f = 0; f < 4; f++) {
        #pragma unroll
        for (int r = 0; r < 4; r++) {
            __bf16 hv = (__bf16)(o[f][r] * invl[r]);
            ob[(size_t)r * 1024 + f * 16] = *(u16*)&hv;
        }
    }
}

// ---------------- launcher ----------------
extern "C" void kernel_launch(void* const* d_in, const int* in_sizes, int n_in,
                              void* d_out, int out_size, void* d_ws, size_t ws_size,
                              hipStream_t stream) {
    const float* hidden = (const float*)d_in[0];
    const float* enc    = (const float*)d_in[1];
    const float* Wq = (const float*)d_in[2];
    const float* Wk = (const float*)d_in[3];
    const float* Wv = (const float*)d_in[4];
    const float* Wo = (const float*)d_in[5];
    const float* bo = (const float*)d_in[6];
    const float* Wg = (const float*)d_in[7];
    const float* bg = (const float*)d_in[8];
    float* out = (float*)d_out;

    char* ws = (char*)d_ws;
    size_t off = 0;
    auto alloc = [&](size_t bytes) -> char* {
        char* p = ws + off;
        off += (bytes + 255) & ~(size_t)255;
        return p;
    };
    u16* hbf   = (u16*)alloc(4096ull * 1024 * 2);
    u16* ebf   = (u16*)alloc(32768ull * 1024 * 2);
    u16* WqT   = (u16*)alloc(1024ull * 1024 * 2);
    u16* WkvT  = (u16*)alloc(2048ull * 1024 * 2);
    u16* WgT   = (u16*)alloc(1024ull * 1024 * 2);
    u16* WoT   = (u16*)alloc(1024ull * 1024 * 2);
    u16* q_bf  = (u16*)alloc(4096ull * 1024 * 2);
    float* hm  = (float*)alloc(2ull * 1024 * 4);
    float* part = (float*)alloc(2ull * 128 * 1024 * 4);
    u16* z_bf  = (u16*)alloc(32ull * 1024 * 2);
    float* scor = (float*)alloc(32ull * 16384 * 4);
    int* sel    = (int*)alloc(32ull * 2048 * 4);
    u16* ksel   = (u16*)alloc(32ull * 2048 * 64 * 2);
    u16* vT     = (u16*)alloc(32ull * 64 * 2048 * 2);
    u16* attn   = (u16*)alloc(4096ull * 1024 * 2);
    u16* gate   = (u16*)alloc(4096ull * 1024 * 2);
    (void)ws_size; (void)in_sizes; (void)n_in; (void)out_size;

    hsum1_kernel<<<dim3(2, 128), 256, 0, stream>>>(hidden, part);
    hsum2_kernel<<<2, 256, 0, stream>>>(part, hm);
    cast_bf16_kernel<<<4096, 256, 0, stream>>>(hidden, hbf, 1048576);
    transpose_cast_kernel<<<dim3(32, 32, 5), dim3(32, 8), 0, stream>>>(
        Wq, Wk, Wv, Wg, Wo, WqT, WkvT, WgT, WoT);

    qz_kernel<<<32, 256, 0, stream>>>(hm, WqT, WkvT, z_bf);
    escore_kernel<<<dim3(128, 2), 256, 0, stream>>>(enc, z_bf, ebf, scor);
    select_kernel<<<32, 1024, 0, stream>>>(scor, sel);
    selproj_kernel<<<dim3(16, 32), 256, 0, stream>>>(ebf, WkvT, sel, ksel, vT);

    gemm_bf16<0><<<dim3(8, 32), 256, 0, stream>>>(hbf, WqT, 1024, q_bf, nullptr, nullptr, nullptr, nullptr);
    attn_kernel<<<dim3(16, 32), 512, 0, stream>>>(q_bf, ksel, vT, attn);

    gemm_bf16<2><<<dim3(8, 32), 256, 0, stream>>>(attn, WgT, 1024, gate, bg, attn, nullptr, nullptr);
    gemm_bf16<3><<<dim3(8, 32), 256, 0, stream>>>(gate, WoT, 1024, nullptr, bo, nullptr, hidden, out);
}

// Round 10
// 252.244 us; speedup vs baseline: 1.5783x; 1.0072x over previous
//
#include <hip/hip_runtime.h>
#include <hip/hip_bf16.h>

typedef unsigned short u16;
typedef __bf16 bf16x8 __attribute__((ext_vector_type(8)));
typedef float f32x4 __attribute__((ext_vector_type(4)));

__device__ __forceinline__ u16 f2bf(float f) {
    union { float f; unsigned int u; } v; v.f = f;
    unsigned int u = v.u;
    unsigned int r = (u + 0x7fffu + ((u >> 16) & 1u)) >> 16;
    return (u16)r;
}
__device__ __forceinline__ float bf2f(u16 b) {
    union { unsigned int u; float f; } v; v.u = ((unsigned int)b) << 16;
    return v.f;
}

__device__ __forceinline__ void glds16(const u16* g, u16* l) {
    __builtin_amdgcn_global_load_lds(
        (__attribute__((address_space(1))) void*)(g),
        (__attribute__((address_space(3))) void*)(l), 16, 0, 0);
}

// ---------------- cast fp32 -> bf16 (hidden only) ----------------
__global__ __launch_bounds__(256) void cast_bf16_kernel(const float* __restrict__ src,
                                                        u16* __restrict__ dst, int n4) {
    int i = blockIdx.x * 256 + threadIdx.x;
    if (i >= n4) return;
    float4 v = ((const float4*)src)[i];
    ushort4 o;
    o.x = f2bf(v.x); o.y = f2bf(v.y); o.z = f2bf(v.z); o.w = f2bf(v.w);
    ((ushort4*)dst)[i] = o;
}

// ---------------- transpose+cast weights: WT[n][k] = W[k][n] ----------------
__global__ __launch_bounds__(256) void transpose_cast_kernel(
    const float* __restrict__ Wq, const float* __restrict__ Wk, const float* __restrict__ Wv,
    const float* __restrict__ Wg, const float* __restrict__ Wo,
    u16* __restrict__ WqT, u16* __restrict__ WkvT, u16* __restrict__ WgT, u16* __restrict__ WoT) {
    __shared__ float tile[32][33];
    const float* src; u16* dst;
    switch (blockIdx.z) {
        case 0: src = Wq; dst = WqT; break;
        case 1: src = Wk; dst = WkvT; break;
        case 2: src = Wv; dst = WkvT + (size_t)1024 * 1024; break;
        case 3: src = Wg; dst = WgT; break;
        default: src = Wo; dst = WoT; break;
    }
    int n0 = blockIdx.x * 32, k0 = blockIdx.y * 32;
    int tx = threadIdx.x, ty = threadIdx.y;   // (32, 8)
    #pragma unroll
    for (int j = 0; j < 4; j++)
        tile[ty + j * 8][tx] = src[(size_t)(k0 + ty + j * 8) * 1024 + n0 + tx];
    __syncthreads();
    #pragma unroll
    for (int j = 0; j < 4; j++)
        dst[(size_t)(n0 + ty + j * 8) * 1024 + k0 + tx] = f2bf(tile[tx][ty + j * 8]);
}

// ---------------- 128^2 bf16 MFMA GEMM (m97 structure) ----------------
template <int EPI>
__global__ __launch_bounds__(256) void gemm_bf16(
    const u16* __restrict__ A, const u16* __restrict__ B, int ldc,
    u16* __restrict__ Cbf, const float* __restrict__ bias,
    const u16* __restrict__ mul_src, const float* __restrict__ add_src,
    float* __restrict__ Cf) {
    constexpr int K = 1024;
    const int tid = threadIdx.x;
    const int w = tid >> 6, l = tid & 63;
    const int lr = l & 15, lg = l >> 4;
    const int wr = w >> 1, wc = w & 1;
    const int m0 = blockIdx.y * 128, n0 = blockIdx.x * 128;

    __shared__ u16 As[128 * 64];
    __shared__ u16 Bs[128 * 64];

    const f32x4 fz = {0.f, 0.f, 0.f, 0.f};
    f32x4 acc[4][4];
    #pragma unroll
    for (int i = 0; i < 4; i++)
        #pragma unroll
        for (int j = 0; j < 4; j++) acc[i][j] = fz;

    const int lane_row = l >> 3;
    const int lane_sl  = l & 7;
    const int src_ch   = lane_sl ^ lane_row;
    const u16* Ab = A + (size_t)(m0 + w * 32 + lane_row) * K + src_ch * 8;
    const u16* Bb = B + (size_t)(n0 + w * 32 + lane_row) * K + src_ch * 8;

    for (int kt = 0; kt < K; kt += 64) {
        __syncthreads();
        #pragma unroll
        for (int j = 0; j < 4; j++) {
            glds16(Ab + (size_t)j * 8 * K + kt, As + (w * 32 + j * 8) * 64);
            glds16(Bb + (size_t)j * 8 * K + kt, Bs + (w * 32 + j * 8) * 64);
        }
        __syncthreads();
        #pragma unroll
        for (int kk = 0; kk < 2; kk++) {
            bf16x8 af[4], bfr[4];
            #pragma unroll
            for (int mi = 0; mi < 4; mi++) {
                int row = wr * 64 + mi * 16 + lr;
                int ch = (kk * 4 + lg) ^ (row & 7);
                af[mi] = *(const bf16x8*)(As + row * 64 + ch * 8);
            }
            #pragma unroll
            for (int ni = 0; ni < 4; ni++) {
                int row = wc * 64 + ni * 16 + lr;
                int ch = (kk * 4 + lg) ^ (row & 7);
                bfr[ni] = *(const bf16x8*)(Bs + row * 64 + ch * 8);
            }
            #pragma unroll
            for (int mi = 0; mi < 4; mi++)
                #pragma unroll
                for (int ni = 0; ni < 4; ni++)
                    acc[mi][ni] = __builtin_amdgcn_mfma_f32_16x16x32_bf16(
                        af[mi], bfr[ni], acc[mi][ni], 0, 0, 0);
        }
    }

    #pragma unroll
    for (int mi = 0; mi < 4; mi++) {
        #pragma unroll
        for (int ni = 0; ni < 4; ni++) {
            #pragma unroll
            for (int r = 0; r < 4; r++) {
                int gm = m0 + wr * 64 + mi * 16 + lg * 4 + r;
                int gn = n0 + wc * 64 + ni * 16 + lr;
                float v = acc[mi][ni][r];
                if (EPI == 0) {
                    Cbf[(size_t)gm * ldc + gn] = f2bf(v);
                } else if (EPI == 2) {
                    float g = v + bias[gn];
                    float a = bf2f(mul_src[(size_t)gm * ldc + gn]);
                    float sg = 1.f / (1.f + __expf(-g));
                    Cbf[(size_t)gm * ldc + gn] = f2bf(a * sg);
                } else {
                    Cf[(size_t)gm * ldc + gn] = v + bias[gn] + add_src[(size_t)gm * ldc + gn];
                }
            }
        }
    }
}

// ---------------- hidden column-sum, stage 1 ----------------
__global__ __launch_bounds__(256) void hsum1_kernel(const float* __restrict__ hidden,
                                                    float* __restrict__ part) {
    int b = blockIdx.x, chunk = blockIdx.y;   // (2, 128)
    int tid = threadIdx.x;
    const float4* src = (const float4*)(hidden + ((size_t)b * 2048 + chunk * 16) * 1024) + tid;
    float4 acc = {0.f, 0.f, 0.f, 0.f};
    #pragma unroll
    for (int r = 0; r < 16; r++) {
        float4 v = src[r * 256];
        acc.x += v.x; acc.y += v.y; acc.z += v.z; acc.w += v.w;
    }
    ((float4*)(part + ((size_t)b * 128 + chunk) * 1024))[tid] = acc;
}

// ---------------- stage 2: mean ----------------
__global__ __launch_bounds__(256) void hsum2_kernel(const float* __restrict__ part,
                                                    float* __restrict__ hm) {
    int b = blockIdx.x, tid = threadIdx.x;
    const float4* src = (const float4*)(part + (size_t)b * 128 * 1024) + tid;
    float4 acc = {0.f, 0.f, 0.f, 0.f};
    for (int c = 0; c < 128; c++) {
        float4 v = src[c * 256];
        acc.x += v.x; acc.y += v.y; acc.z += v.z; acc.w += v.w;
    }
    const float inv = 1.f / 2048.f;
    acc.x *= inv; acc.y *= inv; acc.z *= inv; acc.w *= inv;
    ((float4*)(hm + (size_t)b * 1024))[tid] = acc;
}

// ---------------- qz ----------------
__global__ __launch_bounds__(256) void qz_kernel(const float* __restrict__ hm,
                                                 const u16* __restrict__ WqT,
                                                 const u16* __restrict__ WkT,
                                                 u16* __restrict__ z_bf) {
    int bh = blockIdx.x, b = bh >> 4, h = bh & 15;
    int tid = threadIdx.x;
    __shared__ float hm_l[1024];
    __shared__ float qs_l[64];
    __shared__ float red[256];
    ((float4*)hm_l)[tid] = ((const float4*)(hm + (size_t)b * 1024))[tid];
    __syncthreads();
    {
        int d = tid >> 2, q = tid & 3;
        const u16* wq = WqT + (size_t)(h * 64 + d) * 1024 + q * 256;
        float a = 0.f;
        for (int i = 0; i < 256; i += 8) {
            uint4 u = *(const uint4*)(wq + i);
            const u16* p = (const u16*)&u;
            #pragma unroll
            for (int j = 0; j < 8; j++) a += bf2f(p[j]) * hm_l[q * 256 + i + j];
        }
        red[tid] = a;
    }
    __syncthreads();
    if (tid < 64)
        qs_l[tid] = red[tid * 4] + red[tid * 4 + 1] + red[tid * 4 + 2] + red[tid * 4 + 3];
    __syncthreads();
    {
        float z0 = 0.f, z1 = 0.f, z2 = 0.f, z3 = 0.f;
        for (int d = 0; d < 64; d++) {
            float qs = qs_l[d];
            const u16* wk = WkT + (size_t)(h * 64 + d) * 1024 + tid * 4;
            uint2 u = *(const uint2*)wk;
            const u16* p = (const u16*)&u;
            z0 += qs * bf2f(p[0]); z1 += qs * bf2f(p[1]);
            z2 += qs * bf2f(p[2]); z3 += qs * bf2f(p[3]);
        }
        ushort4 o;
        o.x = f2bf(z0); o.y = f2bf(z1); o.z = f2bf(z2); o.w = f2bf(z3);
        *(ushort4*)(z_bf + (size_t)bh * 1024 + tid * 4) = o;
    }
}

// ---------------- escore v2: fused enc cast + selection score ----------------
// 64 kv rows/block, grid (256,2)=512 blocks. z A-frags read from global (L2-hot).
__global__ __launch_bounds__(256) void escore_kernel(const float* __restrict__ enc,
                                                     const u16* __restrict__ z_bf,
                                                     u16* __restrict__ ebf,
                                                     float* __restrict__ score) {
    const int b = blockIdx.y, kv0 = blockIdx.x * 64;
    const int tid = threadIdx.x, w = tid >> 6, l = tid & 63;
    const int lr = l & 15, lg = l >> 4;
    __shared__ u16 e_lds[64 * 64];   // 8 KB

    const int row2 = tid >> 3;       // 0..31 (rows row2, row2+32)
    const int cgrp = tid & 7;        // 8-float column group
    const float* ebase = enc + (size_t)(b * 16384 + kv0) * 1024;
    u16* obase = ebf + (size_t)(b * 16384 + kv0) * 1024;
    const u16* zb = z_bf + (size_t)b * 16 * 1024;

    float4 rv[2][2];
    auto loadT = [&](int kt) {
        #pragma unroll
        for (int jj = 0; jj < 2; jj++) {
            int row = row2 + jj * 32;
            rv[jj][0] = *(const float4*)(ebase + (size_t)row * 1024 + kt + cgrp * 8);
            rv[jj][1] = *(const float4*)(ebase + (size_t)row * 1024 + kt + cgrp * 8 + 4);
        }
    };
    loadT(0);

    const f32x4 fz = {0.f, 0.f, 0.f, 0.f};
    f32x4 acc = fz;

    for (int kt = 0; kt < 1024; kt += 64) {
        #pragma unroll
        for (int jj = 0; jj < 2; jj++) {
            int row = row2 + jj * 32;
            union { u16 u[8]; uint4 v; } pk;
            pk.u[0] = f2bf(rv[jj][0].x); pk.u[1] = f2bf(rv[jj][0].y);
            pk.u[2] = f2bf(rv[jj][0].z); pk.u[3] = f2bf(rv[jj][0].w);
            pk.u[4] = f2bf(rv[jj][1].x); pk.u[5] = f2bf(rv[jj][1].y);
            pk.u[6] = f2bf(rv[jj][1].z); pk.u[7] = f2bf(rv[jj][1].w);
            *(uint4*)(e_lds + row * 64 + ((cgrp ^ (row & 7)) * 8)) = pk.v;
            *(uint4*)(obase + (size_t)row * 1024 + kt + cgrp * 8) = pk.v;
        }
        __syncthreads();           // e_lds ready
        if (kt + 64 < 1024) loadT(kt + 64);
        #pragma unroll
        for (int ks = 0; ks < 2; ks++) {
            bf16x8 af = *(const bf16x8*)(zb + (size_t)lr * 1024 + kt + ks * 32 + lg * 8);
            int brow = w * 16 + lr;
            bf16x8 bf_ = *(const bf16x8*)(e_lds + brow * 64 + (((ks * 4 + lg) ^ (brow & 7))) * 8);
            acc = __builtin_amdgcn_mfma_f32_16x16x32_bf16(af, bf_, acc, 0, 0, 0);
        }
        __syncthreads();           // before e_lds overwrite
    }
    #pragma unroll
    for (int r = 0; r < 4; r++)
        score[(size_t)(b * 16 + lg * 4 + r) * 16384 + kv0 + w * 16 + lr] = acc[r];
}

// ---------------- top-2048 select: 16-bit keys, single sweep, 1024 threads ----------------
__global__ __launch_bounds__(1024) void select_kernel(const float* __restrict__ score,
                                                      int* __restrict__ sel_idx) {
    const int bh = blockIdx.x;
    const float* sc = score + (size_t)bh * 16384;
    const int tid = threadIdx.x;
    const int grp = tid >> 8;

    __shared__ int hist[4][256];
    __shared__ int total[256];
    __shared__ int bc[4];

    u16 key[16];
    #pragma unroll
    for (int j = 0; j < 16; j++) {
        unsigned int b = __float_as_uint(sc[tid + j * 1024]);
        unsigned int ui = (b & 0x80000000u) ? ~b : (b | 0x80000000u);
        key[j] = (u16)(ui >> 16);
    }

    ((int*)hist)[tid] = 0;
    __syncthreads();
    #pragma unroll
    for (int j = 0; j < 16; j++) atomicAdd(&hist[grp][key[j] >> 8], 1);
    __syncthreads();
    if (tid < 256) total[tid] = hist[0][tid] + hist[1][tid] + hist[2][tid] + hist[3][tid];
    __syncthreads();
    if (tid == 0) {
        int want = 2048, acc = 0;
        for (int dd = 255; dd >= 0; dd--) {
            acc += total[dd];
            if (acc >= want) { bc[0] = dd; bc[1] = want - (acc - total[dd]); break; }
        }
    }
    __syncthreads();
    const int hi = bc[0];
    const int want1 = bc[1];

    ((int*)hist)[tid] = 0;
    __syncthreads();
    #pragma unroll
    for (int j = 0; j < 16; j++)
        if ((key[j] >> 8) == hi) atomicAdd(&hist[grp][key[j] & 0xff], 1);
    __syncthreads();
    if (tid < 256) total[tid] = hist[0][tid] + hist[1][tid] + hist[2][tid] + hist[3][tid];
    __syncthreads();
    if (tid == 0) {
        int want = want1, acc = 0;
        for (int dd = 255; dd >= 0; dd--) {
            acc += total[dd];
            if (acc >= want) { bc[0] = (hi << 8) | dd; bc[1] = want - (acc - total[dd]); break; }
        }
        bc[2] = 0; bc[3] = 0;
    }
    __syncthreads();
    const u16 thr = (u16)bc[0];
    const int n_eq = bc[1];
    const int base_eq = 2048 - n_eq;

    int* out = sel_idx + (size_t)bh * 2048;
    #pragma unroll
    for (int j = 0; j < 16; j++) {
        int i = tid + j * 1024;
        if (key[j] > thr) {
            int p = atomicAdd(&bc[2], 1);
            out[p] = i;
        } else if (key[j] == thr) {
            int p = atomicAdd(&bc[3], 1);
            if (p < n_eq) out[base_eq + p] = i;
        }
    }
}

// ---------------- selected projection: K_sel (chunk-swz) + V_selT (kappa-permuted, chunk-swz) ----
__global__ __launch_bounds__(256) void selproj_kernel(const u16* __restrict__ ebf,
                                                      const u16* __restrict__ WkvT,
                                                      const int* __restrict__ sel_idx,
                                                      u16* __restrict__ k_sel,
                                                      u16* __restrict__ v_selT) {
    const int bh = blockIdx.y, b = bh >> 4, h = bh & 15;
    const int t0 = blockIdx.x * 128;
    const int tid = threadIdx.x, w = tid >> 6, l = tid & 63;
    const int lr = l & 15, lg = l >> 4;
    const int lane_row = l >> 3, src_ch = (l & 7) ^ lane_row;

    __shared__ u16 e_lds[128 * 64];
    __shared__ u16 w_lds[128 * 64];

    int encrow[4], wrow[4];
    #pragma unroll
    for (int j = 0; j < 4; j++) {
        int t = t0 + w * 32 + j * 8 + lane_row;
        encrow[j] = b * 16384 + sel_idx[(size_t)bh * 2048 + t];
        int r = w * 32 + j * 8 + lane_row;
        wrow[j] = (r < 64) ? (h * 64 + r) : (1024 + h * 64 + (r & 63));
    }

    const f32x4 fz = {0.f, 0.f, 0.f, 0.f};
    f32x4 acc_k[2][4], acc_v[8];
    #pragma unroll
    for (int i = 0; i < 2; i++)
        #pragma unroll
        for (int j = 0; j < 4; j++) acc_k[i][j] = fz;
    #pragma unroll
    for (int i = 0; i < 8; i++) acc_v[i] = fz;

    for (int kt = 0; kt < 1024; kt += 64) {
        __syncthreads();
        #pragma unroll
        for (int j = 0; j < 4; j++) {
            glds16(ebf + (size_t)encrow[j] * 1024 + kt + src_ch * 8, e_lds + (w * 32 + j * 8) * 64);
            glds16(WkvT + (size_t)wrow[j] * 1024 + kt + src_ch * 8, w_lds + (w * 32 + j * 8) * 64);
        }
        __syncthreads();
        #pragma unroll
        for (int ks = 0; ks < 2; ks++) {
            bf16x8 ae[2];
            #pragma unroll
            for (int mi = 0; mi < 2; mi++) {
                int row = w * 32 + mi * 16 + lr;
                ae[mi] = *(const bf16x8*)(e_lds + row * 64 + (((ks * 4 + lg) ^ (row & 7))) * 8);
            }
            bf16x8 aw;
            {
                int row = 64 + w * 16 + lr;
                aw = *(const bf16x8*)(w_lds + row * 64 + (((ks * 4 + lg) ^ (row & 7))) * 8);
            }
            #pragma unroll
            for (int ni = 0; ni < 4; ni++) {
                int row = ni * 16 + lr;
                bf16x8 bw = *(const bf16x8*)(w_lds + row * 64 + (((ks * 4 + lg) ^ (row & 7))) * 8);
                acc_k[0][ni] = __builtin_amdgcn_mfma_f32_16x16x32_bf16(ae[0], bw, acc_k[0][ni], 0, 0, 0);
                acc_k[1][ni] = __builtin_amdgcn_mfma_f32_16x16x32_bf16(ae[1], bw, acc_k[1][ni], 0, 0, 0);
            }
            #pragma unroll
            for (int ni = 0; ni < 8; ni++) {
                int row = ni * 16 + lr;
                bf16x8 be = *(const bf16x8*)(e_lds + row * 64 + (((ks * 4 + lg) ^ (row & 7))) * 8);
                acc_v[ni] = __builtin_amdgcn_mfma_f32_16x16x32_bf16(aw, be, acc_v[ni], 0, 0, 0);
            }
        }
    }

    u16* kb = k_sel + (size_t)bh * 2048 * 64;
    #pragma unroll
    for (int mi = 0; mi < 2; mi++)
        #pragma unroll
        for (int ni = 0; ni < 4; ni++)
            #pragma unroll
            for (int r = 0; r < 4; r++) {
                int t = t0 + w * 32 + mi * 16 + lg * 4 + r;
                int d = ni * 16 + lr;
                kb[(size_t)t * 64 + (((d >> 3) ^ (t & 7)) * 8) + (d & 7)] = f2bf(acc_k[mi][ni][r]);
            }
    u16* vb = v_selT + (size_t)bh * 64 * 2048;
    #pragma unroll
    for (int ni = 0; ni < 8; ni++)
        #pragma unroll
        for (int r = 0; r < 4; r++) {
            int d = w * 16 + lg * 4 + r;
            int t = t0 + ni * 16 + lr;
            int tl = t & 63;
            int kap = (tl & 15) * 4 + (tl >> 4);
            vb[(size_t)d * 2048 + (t & ~63) + (((kap >> 3) ^ (d & 7)) * 8) + (kap & 7)] =
                f2bf(acc_v[ni][r]);
        }
}

// ---------------- flash attention: 8 waves, QBLK=128, kappa-packed P store ----------------
__global__ __launch_bounds__(512) void attn_kernel(
    const u16* __restrict__ q_bf, const u16* __restrict__ k_sel,
    const u16* __restrict__ v_selT, u16* __restrict__ attn_out) {
    const int bh = blockIdx.y, b = bh >> 4, h = bh & 15;
    const int q0 = blockIdx.x * 128;
    const int tid = threadIdx.x, w = tid >> 6, l = tid & 63;
    const int lr = l & 15, lg = l >> 4;
    const int lk = lr & 7;
    const float SC = 0.18033688011f;   // 0.125 * log2(e)
    const float THR = 11.0f;

    __shared__ u16 k_lds[2][64 * 64];
    __shared__ u16 vt_lds[64 * 64];
    __shared__ u16 p_lds[8][16][68];

    const u16* qb = q_bf + ((size_t)b * 2048 + q0 + w * 16 + lr) * 1024 + h * 64;
    bf16x8 qf0 = *(const bf16x8*)(qb + lg * 8);
    bf16x8 qf1 = *(const bf16x8*)(qb + 32 + lg * 8);

    const f32x4 fz = {0.f, 0.f, 0.f, 0.f};
    f32x4 o[4];
    #pragma unroll
    for (int f = 0; f < 4; f++) o[f] = fz;
    float mm = -1e30f;
    float l_part[4] = {0.f, 0.f, 0.f, 0.f};

    const u16* kb  = k_sel + (size_t)bh * 2048 * 64;
    const u16* vtb = v_selT + (size_t)bh * 64 * 2048;

    auto stageK = [&](int it, int buf) {
        const u16* ksrc = kb + (size_t)(it * 64 + w * 8) * 64 + (size_t)l * 8;
        glds16(ksrc, k_lds[buf] + (w * 8) * 64);
    };
    auto stageV = [&](int it) {
        const u16* vsrc = vtb + (size_t)(w * 8 + (l >> 3)) * 2048 + it * 64 + (l & 7) * 8;
        glds16(vsrc, vt_lds + (w * 8) * 64);
    };

    stageK(0, 0);
    __syncthreads();

    #pragma unroll 1
    for (int it = 0; it < 32; ++it) {
        const int cur = it & 1;
        stageV(it);
        if (it + 1 < 32) stageK(it + 1, cur ^ 1);

        f32x4 s[4];
        #pragma unroll
        for (int c = 0; c < 4; c++) s[c] = fz;
        __builtin_amdgcn_s_setprio(1);
        #pragma unroll
        for (int c = 0; c < 4; c++) {
            const u16* krow = k_lds[cur] + (c * 16 + lr) * 64;
            bf16x8 kf0 = *(const bf16x8*)(krow + (lg ^ lk) * 8);
            s[c] = __builtin_amdgcn_mfma_f32_16x16x32_bf16(qf0, kf0, s[c], 0, 0, 0);
            bf16x8 kf1 = *(const bf16x8*)(krow + (((4 + lg) ^ lk)) * 8);
            s[c] = __builtin_amdgcn_mfma_f32_16x16x32_bf16(qf1, kf1, s[c], 0, 0, 0);
        }
        __builtin_amdgcn_s_setprio(0);

        float mx = s[0][0];
        #pragma unroll
        for (int c = 0; c < 4; c++)
            #pragma unroll
            for (int r = 0; r < 4; r++) mx = fmaxf(mx, s[c][r]);
        mx = fmaxf(mx, __shfl_xor(mx, 1));
        mx = fmaxf(mx, __shfl_xor(mx, 2));
        mx = fmaxf(mx, __shfl_xor(mx, 4));
        mx = fmaxf(mx, __shfl_xor(mx, 8));
        mx = fmaxf(mx, __shfl_xor(mx, 16));
        mx = fmaxf(mx, __shfl_xor(mx, 32));
        mx *= SC;
        if (mx > mm + THR) {
            float al = __builtin_amdgcn_exp2f(mm - mx);
            mm = mx;
            #pragma unroll
            for (int r = 0; r < 4; r++) l_part[r] *= al;
            #pragma unroll
            for (int f = 0; f < 4; f++)
                #pragma unroll
                for (int r = 0; r < 4; r++) o[f][r] *= al;
        }
        #pragma unroll
        for (int r = 0; r < 4; r++) {
            ushort4 pk;
            u16 pb[4];
            #pragma unroll
            for (int c = 0; c < 4; c++) {
                float p = __builtin_amdgcn_exp2f(__builtin_fmaf(s[c][r], SC, -mm));
                l_part[r] += p;
                __bf16 hv = (__bf16)p;
                pb[c] = *(u16*)&hv;
            }
            pk.x = pb[0]; pk.y = pb[1]; pk.z = pb[2]; pk.w = pb[3];
            *(ushort4*)(&p_lds[w][lg * 4 + r][lr * 4]) = pk;
        }

        if (it + 1 < 32) {
            asm volatile("s_waitcnt vmcnt(1)" ::: "memory");
        } else {
            asm volatile("s_waitcnt vmcnt(0)" ::: "memory");
        }
        __builtin_amdgcn_sched_barrier(0);
        __builtin_amdgcn_s_barrier();

        __builtin_amdgcn_s_setprio(1);
        #pragma unroll
        for (int kk = 0; kk < 2; kk++) {
            bf16x8 ap = *(const bf16x8*)(&p_lds[w][lr][kk * 32 + lg * 8]);
            #pragma unroll
            for (int f = 0; f < 4; f++) {
                const u16* vrow = vt_lds + (f * 16 + lr) * 64;
                bf16x8 bv = *(const bf16x8*)(vrow + (((kk * 4 + lg) ^ lk)) * 8);
                o[f] = __builtin_amdgcn_mfma_f32_16x16x32_bf16(ap, bv, o[f], 0, 0, 0);
            }
        }
        __builtin_amdgcn_s_setprio(0);

        __syncthreads();
    }

    float invl[4];
    #pragma unroll
    for (int r = 0; r < 4; r++) {
        float lr_ = l_part[r];
        lr_ += __shfl_xor(lr_, 1);
        lr_ += __shfl_xor(lr_, 2);
        lr_ += __shfl_xor(lr_, 4);
        lr_ += __shfl_xor(lr_, 8);
        invl[r] = 1.f / lr_;
    }
    u16* ob = attn_out + ((size_t)b * 2048 + q0 + w * 16 + lg * 4) * 1024 + h * 64 + lr;
    #pragma unroll
    for (int f = 0; f < 4; f++) {
        #pragma unroll
        for (int r = 0; r < 4; r++) {
            __bf16 hv = (__bf16)(o[f][r] * invl[r]);
            ob[(size_t)r * 1024 + f * 16] = *(u16*)&hv;
        }
    }
}

// ---------------- launcher ----------------
extern "C" void kernel_launch(void* const* d_in, const int* in_sizes, int n_in,
                              void* d_out, int out_size, void* d_ws, size_t ws_size,
                              hipStream_t stream) {
    const float* hidden = (const float*)d_in[0];
    const float* enc    = (const float*)d_in[1];
    const float* Wq = (const float*)d_in[2];
    const float* Wk = (const float*)d_in[3];
    const float* Wv = (const float*)d_in[4];
    const float* Wo = (const float*)d_in[5];
    const float* bo = (const float*)d_in[6];
    const float* Wg = (const float*)d_in[7];
    const float* bg = (const float*)d_in[8];
    float* out = (float*)d_out;

    char* ws = (char*)d_ws;
    size_t off = 0;
    auto alloc = [&](size_t bytes) -> char* {
        char* p = ws + off;
        off += (bytes + 255) & ~(size_t)255;
        return p;
    };
    u16* hbf   = (u16*)alloc(4096ull * 1024 * 2);
    u16* ebf   = (u16*)alloc(32768ull * 1024 * 2);
    u16* WqT   = (u16*)alloc(1024ull * 1024 * 2);
    u16* WkvT  = (u16*)alloc(2048ull * 1024 * 2);
    u16* WgT   = (u16*)alloc(1024ull * 1024 * 2);
    u16* WoT   = (u16*)alloc(1024ull * 1024 * 2);
    u16* q_bf  = (u16*)alloc(4096ull * 1024 * 2);
    float* hm  = (float*)alloc(2ull * 1024 * 4);
    float* part = (float*)alloc(2ull * 128 * 1024 * 4);
    u16* z_bf  = (u16*)alloc(32ull * 1024 * 2);
    float* scor = (float*)alloc(32ull * 16384 * 4);
    int* sel    = (int*)alloc(32ull * 2048 * 4);
    u16* ksel   = (u16*)alloc(32ull * 2048 * 64 * 2);
    u16* vT     = (u16*)alloc(32ull * 64 * 2048 * 2);
    u16* attn   = (u16*)alloc(4096ull * 1024 * 2);
    u16* gate   = (u16*)alloc(4096ull * 1024 * 2);
    (void)ws_size; (void)in_sizes; (void)n_in; (void)out_size;

    hsum1_kernel<<<dim3(2, 128), 256, 0, stream>>>(hidden, part);
    hsum2_kernel<<<2, 256, 0, stream>>>(part, hm);
    cast_bf16_kernel<<<4096, 256, 0, stream>>>(hidden, hbf, 1048576);
    transpose_cast_kernel<<<dim3(32, 32, 5), dim3(32, 8), 0, stream>>>(
        Wq, Wk, Wv, Wg, Wo, WqT, WkvT, WgT, WoT);

    qz_kernel<<<32, 256, 0, stream>>>(hm, WqT, WkvT, z_bf);
    escore_kernel<<<dim3(256, 2), 256, 0, stream>>>(enc, z_bf, ebf, scor);
    select_kernel<<<32, 1024, 0, stream>>>(scor, sel);
    selproj_kernel<<<dim3(16, 32), 256, 0, stream>>>(ebf, WkvT, sel, ksel, vT);

    gemm_bf16<0><<<dim3(8, 32), 256, 0, stream>>>(hbf, WqT, 1024, q_bf, nullptr, nullptr, nullptr, nullptr);
    attn_kernel<<<dim3(16, 32), 512, 0, stream>>>(q_bf, ksel, vT, attn);

    gemm_bf16<2><<<dim3(8, 32), 256, 0, stream>>>(attn, WgT, 1024, gate, bg, attn, nullptr, nullptr);
    gemm_bf16<3><<<dim3(8, 32), 256, 0, stream>>>(gate, WoT, 1024, nullptr, bo, nullptr, hidden, out);
}

// Round 11
// 250.913 us; speedup vs baseline: 1.5867x; 1.0053x over previous
//
#include <hip/hip_runtime.h>
#include <hip/hip_bf16.h>

typedef unsigned short u16;
typedef __bf16 bf16x8 __attribute__((ext_vector_type(8)));
typedef float f32x4 __attribute__((ext_vector_type(4)));

__device__ __forceinline__ u16 f2bf(float f) {
    union { float f; unsigned int u; } v; v.f = f;
    unsigned int u = v.u;
    unsigned int r = (u + 0x7fffu + ((u >> 16) & 1u)) >> 16;
    return (u16)r;
}
__device__ __forceinline__ float bf2f(u16 b) {
    union { unsigned int u; float f; } v; v.u = ((unsigned int)b) << 16;
    return v.f;
}

__device__ __forceinline__ void glds16(const u16* g, u16* l) {
    __builtin_amdgcn_global_load_lds(
        (__attribute__((address_space(1))) void*)(g),
        (__attribute__((address_space(3))) void*)(l), 16, 0, 0);
}

// ---------------- cast fp32 -> bf16 (hidden only) ----------------
__global__ __launch_bounds__(256) void cast_bf16_kernel(const float* __restrict__ src,
                                                        u16* __restrict__ dst, int n4) {
    int i = blockIdx.x * 256 + threadIdx.x;
    if (i >= n4) return;
    float4 v = ((const float4*)src)[i];
    ushort4 o;
    o.x = f2bf(v.x); o.y = f2bf(v.y); o.z = f2bf(v.z); o.w = f2bf(v.w);
    ((ushort4*)dst)[i] = o;
}

// ---------------- transpose+cast weights: WT[n][k] = W[k][n] ----------------
__global__ __launch_bounds__(256) void transpose_cast_kernel(
    const float* __restrict__ Wq, const float* __restrict__ Wk, const float* __restrict__ Wv,
    const float* __restrict__ Wg, const float* __restrict__ Wo,
    u16* __restrict__ WqT, u16* __restrict__ WkvT, u16* __restrict__ WgT, u16* __restrict__ WoT) {
    __shared__ float tile[32][33];
    const float* src; u16* dst;
    switch (blockIdx.z) {
        case 0: src = Wq; dst = WqT; break;
        case 1: src = Wk; dst = WkvT; break;
        case 2: src = Wv; dst = WkvT + (size_t)1024 * 1024; break;
        case 3: src = Wg; dst = WgT; break;
        default: src = Wo; dst = WoT; break;
    }
    int n0 = blockIdx.x * 32, k0 = blockIdx.y * 32;
    int tx = threadIdx.x, ty = threadIdx.y;   // (32, 8)
    #pragma unroll
    for (int j = 0; j < 4; j++)
        tile[ty + j * 8][tx] = src[(size_t)(k0 + ty + j * 8) * 1024 + n0 + tx];
    __syncthreads();
    #pragma unroll
    for (int j = 0; j < 4; j++)
        dst[(size_t)(n0 + ty + j * 8) * 1024 + k0 + tx] = f2bf(tile[tx][ty + j * 8]);
}

// ---------------- 128^2 bf16 MFMA GEMM (m97 structure) ----------------
template <int EPI>
__global__ __launch_bounds__(256) void gemm_bf16(
    const u16* __restrict__ A, const u16* __restrict__ B, int ldc,
    u16* __restrict__ Cbf, const float* __restrict__ bias,
    const u16* __restrict__ mul_src, const float* __restrict__ add_src,
    float* __restrict__ Cf) {
    constexpr int K = 1024;
    const int tid = threadIdx.x;
    const int w = tid >> 6, l = tid & 63;
    const int lr = l & 15, lg = l >> 4;
    const int wr = w >> 1, wc = w & 1;
    const int m0 = blockIdx.y * 128, n0 = blockIdx.x * 128;

    __shared__ u16 As[128 * 64];
    __shared__ u16 Bs[128 * 64];

    const f32x4 fz = {0.f, 0.f, 0.f, 0.f};
    f32x4 acc[4][4];
    #pragma unroll
    for (int i = 0; i < 4; i++)
        #pragma unroll
        for (int j = 0; j < 4; j++) acc[i][j] = fz;

    const int lane_row = l >> 3;
    const int lane_sl  = l & 7;
    const int src_ch   = lane_sl ^ lane_row;
    const u16* Ab = A + (size_t)(m0 + w * 32 + lane_row) * K + src_ch * 8;
    const u16* Bb = B + (size_t)(n0 + w * 32 + lane_row) * K + src_ch * 8;

    for (int kt = 0; kt < K; kt += 64) {
        __syncthreads();
        #pragma unroll
        for (int j = 0; j < 4; j++) {
            glds16(Ab + (size_t)j * 8 * K + kt, As + (w * 32 + j * 8) * 64);
            glds16(Bb + (size_t)j * 8 * K + kt, Bs + (w * 32 + j * 8) * 64);
        }
        __syncthreads();
        #pragma unroll
        for (int kk = 0; kk < 2; kk++) {
            bf16x8 af[4], bfr[4];
            #pragma unroll
            for (int mi = 0; mi < 4; mi++) {
                int row = wr * 64 + mi * 16 + lr;
                int ch = (kk * 4 + lg) ^ (row & 7);
                af[mi] = *(const bf16x8*)(As + row * 64 + ch * 8);
            }
            #pragma unroll
            for (int ni = 0; ni < 4; ni++) {
                int row = wc * 64 + ni * 16 + lr;
                int ch = (kk * 4 + lg) ^ (row & 7);
                bfr[ni] = *(const bf16x8*)(Bs + row * 64 + ch * 8);
            }
            #pragma unroll
            for (int mi = 0; mi < 4; mi++)
                #pragma unroll
                for (int ni = 0; ni < 4; ni++)
                    acc[mi][ni] = __builtin_amdgcn_mfma_f32_16x16x32_bf16(
                        af[mi], bfr[ni], acc[mi][ni], 0, 0, 0);
        }
    }

    #pragma unroll
    for (int mi = 0; mi < 4; mi++) {
        #pragma unroll
        for (int ni = 0; ni < 4; ni++) {
            #pragma unroll
            for (int r = 0; r < 4; r++) {
                int gm = m0 + wr * 64 + mi * 16 + lg * 4 + r;
                int gn = n0 + wc * 64 + ni * 16 + lr;
                float v = acc[mi][ni][r];
                if (EPI == 0) {
                    Cbf[(size_t)gm * ldc + gn] = f2bf(v);
                } else if (EPI == 2) {
                    float g = v + bias[gn];
                    float a = bf2f(mul_src[(size_t)gm * ldc + gn]);
                    float sg = 1.f / (1.f + __expf(-g));
                    Cbf[(size_t)gm * ldc + gn] = f2bf(a * sg);
                } else {
                    Cf[(size_t)gm * ldc + gn] = v + bias[gn] + add_src[(size_t)gm * ldc + gn];
                }
            }
        }
    }
}

// ---------------- hidden column-sum, stage 1 ----------------
__global__ __launch_bounds__(256) void hsum1_kernel(const float* __restrict__ hidden,
                                                    float* __restrict__ part) {
    int b = blockIdx.x, chunk = blockIdx.y;   // (2, 128)
    int tid = threadIdx.x;
    const float4* src = (const float4*)(hidden + ((size_t)b * 2048 + chunk * 16) * 1024) + tid;
    float4 acc = {0.f, 0.f, 0.f, 0.f};
    #pragma unroll
    for (int r = 0; r < 16; r++) {
        float4 v = src[r * 256];
        acc.x += v.x; acc.y += v.y; acc.z += v.z; acc.w += v.w;
    }
    ((float4*)(part + ((size_t)b * 128 + chunk) * 1024))[tid] = acc;
}

// ---------------- stage 2: mean ----------------
__global__ __launch_bounds__(256) void hsum2_kernel(const float* __restrict__ part,
                                                    float* __restrict__ hm) {
    int b = blockIdx.x, tid = threadIdx.x;
    const float4* src = (const float4*)(part + (size_t)b * 128 * 1024) + tid;
    float4 acc = {0.f, 0.f, 0.f, 0.f};
    for (int c = 0; c < 128; c++) {
        float4 v = src[c * 256];
        acc.x += v.x; acc.y += v.y; acc.z += v.z; acc.w += v.w;
    }
    const float inv = 1.f / 2048.f;
    acc.x *= inv; acc.y *= inv; acc.z *= inv; acc.w *= inv;
    ((float4*)(hm + (size_t)b * 1024))[tid] = acc;
}

// ---------------- qz ----------------
__global__ __launch_bounds__(256) void qz_kernel(const float* __restrict__ hm,
                                                 const u16* __restrict__ WqT,
                                                 const u16* __restrict__ WkT,
                                                 u16* __restrict__ z_bf) {
    int bh = blockIdx.x, b = bh >> 4, h = bh & 15;
    int tid = threadIdx.x;
    __shared__ float hm_l[1024];
    __shared__ float qs_l[64];
    __shared__ float red[256];
    ((float4*)hm_l)[tid] = ((const float4*)(hm + (size_t)b * 1024))[tid];
    __syncthreads();
    {
        int d = tid >> 2, q = tid & 3;
        const u16* wq = WqT + (size_t)(h * 64 + d) * 1024 + q * 256;
        float a = 0.f;
        for (int i = 0; i < 256; i += 8) {
            uint4 u = *(const uint4*)(wq + i);
            const u16* p = (const u16*)&u;
            #pragma unroll
            for (int j = 0; j < 8; j++) a += bf2f(p[j]) * hm_l[q * 256 + i + j];
        }
        red[tid] = a;
    }
    __syncthreads();
    if (tid < 64)
        qs_l[tid] = red[tid * 4] + red[tid * 4 + 1] + red[tid * 4 + 2] + red[tid * 4 + 3];
    __syncthreads();
    {
        float z0 = 0.f, z1 = 0.f, z2 = 0.f, z3 = 0.f;
        for (int d = 0; d < 64; d++) {
            float qs = qs_l[d];
            const u16* wk = WkT + (size_t)(h * 64 + d) * 1024 + tid * 4;
            uint2 u = *(const uint2*)wk;
            const u16* p = (const u16*)&u;
            z0 += qs * bf2f(p[0]); z1 += qs * bf2f(p[1]);
            z2 += qs * bf2f(p[2]); z3 += qs * bf2f(p[3]);
        }
        ushort4 o;
        o.x = f2bf(z0); o.y = f2bf(z1); o.z = f2bf(z2); o.w = f2bf(z3);
        *(ushort4*)(z_bf + (size_t)bh * 1024 + tid * 4) = o;
    }
}

// ---------------- escore v2: fused enc cast + selection score ----------------
// 64 kv rows/block, grid (256,2)=512 blocks. z A-frags read from global (L2-hot).
__global__ __launch_bounds__(256) void escore_kernel(const float* __restrict__ enc,
                                                     const u16* __restrict__ z_bf,
                                                     u16* __restrict__ ebf,
                                                     float* __restrict__ score) {
    const int b = blockIdx.y, kv0 = blockIdx.x * 64;
    const int tid = threadIdx.x, w = tid >> 6, l = tid & 63;
    const int lr = l & 15, lg = l >> 4;
    __shared__ u16 e_lds[64 * 64];   // 8 KB

    const int row2 = tid >> 3;       // 0..31 (rows row2, row2+32)
    const int cgrp = tid & 7;        // 8-float column group
    const float* ebase = enc + (size_t)(b * 16384 + kv0) * 1024;
    u16* obase = ebf + (size_t)(b * 16384 + kv0) * 1024;
    const u16* zb = z_bf + (size_t)b * 16 * 1024;

    float4 rv[2][2];
    auto loadT = [&](int kt) {
        #pragma unroll
        for (int jj = 0; jj < 2; jj++) {
            int row = row2 + jj * 32;
            rv[jj][0] = *(const float4*)(ebase + (size_t)row * 1024 + kt + cgrp * 8);
            rv[jj][1] = *(const float4*)(ebase + (size_t)row * 1024 + kt + cgrp * 8 + 4);
        }
    };
    loadT(0);

    const f32x4 fz = {0.f, 0.f, 0.f, 0.f};
    f32x4 acc = fz;

    for (int kt = 0; kt < 1024; kt += 64) {
        #pragma unroll
        for (int jj = 0; jj < 2; jj++) {
            int row = row2 + jj * 32;
            union { u16 u[8]; uint4 v; } pk;
            pk.u[0] = f2bf(rv[jj][0].x); pk.u[1] = f2bf(rv[jj][0].y);
            pk.u[2] = f2bf(rv[jj][0].z); pk.u[3] = f2bf(rv[jj][0].w);
            pk.u[4] = f2bf(rv[jj][1].x); pk.u[5] = f2bf(rv[jj][1].y);
            pk.u[6] = f2bf(rv[jj][1].z); pk.u[7] = f2bf(rv[jj][1].w);
            *(uint4*)(e_lds + row * 64 + ((cgrp ^ (row & 7)) * 8)) = pk.v;
            *(uint4*)(obase + (size_t)row * 1024 + kt + cgrp * 8) = pk.v;
        }
        __syncthreads();           // e_lds ready
        if (kt + 64 < 1024) loadT(kt + 64);
        #pragma unroll
        for (int ks = 0; ks < 2; ks++) {
            bf16x8 af = *(const bf16x8*)(zb + (size_t)lr * 1024 + kt + ks * 32 + lg * 8);
            int brow = w * 16 + lr;
            bf16x8 bf_ = *(const bf16x8*)(e_lds + brow * 64 + (((ks * 4 + lg) ^ (brow & 7))) * 8);
            acc = __builtin_amdgcn_mfma_f32_16x16x32_bf16(af, bf_, acc, 0, 0, 0);
        }
        __syncthreads();           // before e_lds overwrite
    }
    #pragma unroll
    for (int r = 0; r < 4; r++)
        score[(size_t)(b * 16 + lg * 4 + r) * 16384 + kv0 + w * 16 + lr] = acc[r];
}

// ---------------- top-2048 select: 16-bit keys, single sweep, 1024 threads ----------------
__global__ __launch_bounds__(1024) void select_kernel(const float* __restrict__ score,
                                                      int* __restrict__ sel_idx) {
    const int bh = blockIdx.x;
    const float* sc = score + (size_t)bh * 16384;
    const int tid = threadIdx.x;
    const int grp = tid >> 8;

    __shared__ int hist[4][256];
    __shared__ int total[256];
    __shared__ int bc[4];

    u16 key[16];
    #pragma unroll
    for (int j = 0; j < 16; j++) {
        unsigned int b = __float_as_uint(sc[tid + j * 1024]);
        unsigned int ui = (b & 0x80000000u) ? ~b : (b | 0x80000000u);
        key[j] = (u16)(ui >> 16);
    }

    ((int*)hist)[tid] = 0;
    __syncthreads();
    #pragma unroll
    for (int j = 0; j < 16; j++) atomicAdd(&hist[grp][key[j] >> 8], 1);
    __syncthreads();
    if (tid < 256) total[tid] = hist[0][tid] + hist[1][tid] + hist[2][tid] + hist[3][tid];
    __syncthreads();
    if (tid == 0) {
        int want = 2048, acc = 0;
        for (int dd = 255; dd >= 0; dd--) {
            acc += total[dd];
            if (acc >= want) { bc[0] = dd; bc[1] = want - (acc - total[dd]); break; }
        }
    }
    __syncthreads();
    const int hi = bc[0];
    const int want1 = bc[1];

    ((int*)hist)[tid] = 0;
    __syncthreads();
    #pragma unroll
    for (int j = 0; j < 16; j++)
        if ((key[j] >> 8) == hi) atomicAdd(&hist[grp][key[j] & 0xff], 1);
    __syncthreads();
    if (tid < 256) total[tid] = hist[0][tid] + hist[1][tid] + hist[2][tid] + hist[3][tid];
    __syncthreads();
    if (tid == 0) {
        int want = want1, acc = 0;
        for (int dd = 255; dd >= 0; dd--) {
            acc += total[dd];
            if (acc >= want) { bc[0] = (hi << 8) | dd; bc[1] = want - (acc - total[dd]); break; }
        }
        bc[2] = 0; bc[3] = 0;
    }
    __syncthreads();
    const u16 thr = (u16)bc[0];
    const int n_eq = bc[1];
    const int base_eq = 2048 - n_eq;

    int* out = sel_idx + (size_t)bh * 2048;
    #pragma unroll
    for (int j = 0; j < 16; j++) {
        int i = tid + j * 1024;
        if (key[j] > thr) {
            int p = atomicAdd(&bc[2], 1);
            out[p] = i;
        } else if (key[j] == thr) {
            int p = atomicAdd(&bc[3], 1);
            if (p < n_eq) out[base_eq + p] = i;
        }
    }
}

// ---------------- selected projection: K_sel (chunk-swz) + V_selT (kappa-permuted, chunk-swz) ----
__global__ __launch_bounds__(256) void selproj_kernel(const u16* __restrict__ ebf,
                                                      const u16* __restrict__ WkvT,
                                                      const int* __restrict__ sel_idx,
                                                      u16* __restrict__ k_sel,
                                                      u16* __restrict__ v_selT) {
    const int bh = blockIdx.y, b = bh >> 4, h = bh & 15;
    const int t0 = blockIdx.x * 128;
    const int tid = threadIdx.x, w = tid >> 6, l = tid & 63;
    const int lr = l & 15, lg = l >> 4;
    const int lane_row = l >> 3, src_ch = (l & 7) ^ lane_row;

    __shared__ u16 e_lds[128 * 64];
    __shared__ u16 w_lds[128 * 64];

    int encrow[4], wrow[4];
    #pragma unroll
    for (int j = 0; j < 4; j++) {
        int t = t0 + w * 32 + j * 8 + lane_row;
        encrow[j] = b * 16384 + sel_idx[(size_t)bh * 2048 + t];
        int r = w * 32 + j * 8 + lane_row;
        wrow[j] = (r < 64) ? (h * 64 + r) : (1024 + h * 64 + (r & 63));
    }

    const f32x4 fz = {0.f, 0.f, 0.f, 0.f};
    f32x4 acc_k[2][4], acc_v[8];
    #pragma unroll
    for (int i = 0; i < 2; i++)
        #pragma unroll
        for (int j = 0; j < 4; j++) acc_k[i][j] = fz;
    #pragma unroll
    for (int i = 0; i < 8; i++) acc_v[i] = fz;

    for (int kt = 0; kt < 1024; kt += 64) {
        __syncthreads();
        #pragma unroll
        for (int j = 0; j < 4; j++) {
            glds16(ebf + (size_t)encrow[j] * 1024 + kt + src_ch * 8, e_lds + (w * 32 + j * 8) * 64);
            glds16(WkvT + (size_t)wrow[j] * 1024 + kt + src_ch * 8, w_lds + (w * 32 + j * 8) * 64);
        }
        __syncthreads();
        #pragma unroll
        for (int ks = 0; ks < 2; ks++) {
            bf16x8 ae[2];
            #pragma unroll
            for (int mi = 0; mi < 2; mi++) {
                int row = w * 32 + mi * 16 + lr;
                ae[mi] = *(const bf16x8*)(e_lds + row * 64 + (((ks * 4 + lg) ^ (row & 7))) * 8);
            }
            bf16x8 aw;
            {
                int row = 64 + w * 16 + lr;
                aw = *(const bf16x8*)(w_lds + row * 64 + (((ks * 4 + lg) ^ (row & 7))) * 8);
            }
            #pragma unroll
            for (int ni = 0; ni < 4; ni++) {
                int row = ni * 16 + lr;
                bf16x8 bw = *(const bf16x8*)(w_lds + row * 64 + (((ks * 4 + lg) ^ (row & 7))) * 8);
                acc_k[0][ni] = __builtin_amdgcn_mfma_f32_16x16x32_bf16(ae[0], bw, acc_k[0][ni], 0, 0, 0);
                acc_k[1][ni] = __builtin_amdgcn_mfma_f32_16x16x32_bf16(ae[1], bw, acc_k[1][ni], 0, 0, 0);
            }
            #pragma unroll
            for (int ni = 0; ni < 8; ni++) {
                int row = ni * 16 + lr;
                bf16x8 be = *(const bf16x8*)(e_lds + row * 64 + (((ks * 4 + lg) ^ (row & 7))) * 8);
                acc_v[ni] = __builtin_amdgcn_mfma_f32_16x16x32_bf16(aw, be, acc_v[ni], 0, 0, 0);
            }
        }
    }

    u16* kb = k_sel + (size_t)bh * 2048 * 64;
    #pragma unroll
    for (int mi = 0; mi < 2; mi++)
        #pragma unroll
        for (int ni = 0; ni < 4; ni++)
            #pragma unroll
            for (int r = 0; r < 4; r++) {
                int t = t0 + w * 32 + mi * 16 + lg * 4 + r;
                int d = ni * 16 + lr;
                kb[(size_t)t * 64 + (((d >> 3) ^ (t & 7)) * 8) + (d & 7)] = f2bf(acc_k[mi][ni][r]);
            }
    u16* vb = v_selT + (size_t)bh * 64 * 2048;
    #pragma unroll
    for (int ni = 0; ni < 8; ni++)
        #pragma unroll
        for (int r = 0; r < 4; r++) {
            int d = w * 16 + lg * 4 + r;
            int t = t0 + ni * 16 + lr;
            int tl = t & 63;
            int kap = (tl & 15) * 4 + (tl >> 4);
            vb[(size_t)d * 2048 + (t & ~63) + (((kap >> 3) ^ (d & 7)) * 8) + (kap & 7)] =
                f2bf(acc_v[ni][r]);
        }
}

// ---------------- flash attention: 8 waves, QBLK=128, kappa-packed P store ----------------
__global__ __launch_bounds__(512) void attn_kernel(
    const u16* __restrict__ q_bf, const u16* __restrict__ k_sel,
    const u16* __restrict__ v_selT, u16* __restrict__ attn_out) {
    const int bh = blockIdx.y, b = bh >> 4, h = bh & 15;
    const int q0 = blockIdx.x * 128;
    const int tid = threadIdx.x, w = tid >> 6, l = tid & 63;
    const int lr = l & 15, lg = l >> 4;
    const int lk = lr & 7;
    const float SC = 0.18033688011f;   // 0.125 * log2(e)
    const float THR = 11.0f;

    __shared__ u16 k_lds[2][64 * 64];
    __shared__ u16 vt_lds[64 * 64];
    __shared__ u16 p_lds[8][16][68];

    const u16* qb = q_bf + ((size_t)b * 2048 + q0 + w * 16 + lr) * 1024 + h * 64;
    bf16x8 qf0 = *(const bf16x8*)(qb + lg * 8);
    bf16x8 qf1 = *(const bf16x8*)(qb + 32 + lg * 8);

    const f32x4 fz = {0.f, 0.f, 0.f, 0.f};
    f32x4 o[4];
    #pragma unroll
    for (int f = 0; f < 4; f++) o[f] = fz;
    float mm = -1e30f;
    float l_part[4] = {0.f, 0.f, 0.f, 0.f};

    const u16* kb  = k_sel + (size_t)bh * 2048 * 64;
    const u16* vtb = v_selT + (size_t)bh * 64 * 2048;

    auto stageK = [&](int it, int buf) {
        const u16* ksrc = kb + (size_t)(it * 64 + w * 8) * 64 + (size_t)l * 8;
        glds16(ksrc, k_lds[buf] + (w * 8) * 64);
    };
    auto stageV = [&](int it) {
        const u16* vsrc = vtb + (size_t)(w * 8 + (l >> 3)) * 2048 + it * 64 + (l & 7) * 8;
        glds16(vsrc, vt_lds + (w * 8) * 64);
    };

    stageK(0, 0);
    __syncthreads();

    #pragma unroll 1
    for (int it = 0; it < 32; ++it) {
        const int cur = it & 1;
        stageV(it);
        if (it + 1 < 32) stageK(it + 1, cur ^ 1);

        f32x4 s[4];
        #pragma unroll
        for (int c = 0; c < 4; c++) s[c] = fz;
        __builtin_amdgcn_s_setprio(1);
        #pragma unroll
        for (int c = 0; c < 4; c++) {
            const u16* krow = k_lds[cur] + (c * 16 + lr) * 64;
            bf16x8 kf0 = *(const bf16x8*)(krow + (lg ^ lk) * 8);
            s[c] = __builtin_amdgcn_mfma_f32_16x16x32_bf16(qf0, kf0, s[c], 0, 0, 0);
            bf16x8 kf1 = *(const bf16x8*)(krow + (((4 + lg) ^ lk)) * 8);
            s[c] = __builtin_amdgcn_mfma_f32_16x16x32_bf16(qf1, kf1, s[c], 0, 0, 0);
        }
        __builtin_amdgcn_s_setprio(0);

        float mx = s[0][0];
        #pragma unroll
        for (int c = 0; c < 4; c++)
            #pragma unroll
            for (int r = 0; r < 4; r++) mx = fmaxf(mx, s[c][r]);
        mx = fmaxf(mx, __shfl_xor(mx, 1));
        mx = fmaxf(mx, __shfl_xor(mx, 2));
        mx = fmaxf(mx, __shfl_xor(mx, 4));
        mx = fmaxf(mx, __shfl_xor(mx, 8));
        mx = fmaxf(mx, __shfl_xor(mx, 16));
        mx = fmaxf(mx, __shfl_xor(mx, 32));
        mx *= SC;
        if (mx > mm + THR) {
            float al = __builtin_amdgcn_exp2f(mm - mx);
            mm = mx;
            #pragma unroll
            for (int r = 0; r < 4; r++) l_part[r] *= al;
            #pragma unroll
            for (int f = 0; f < 4; f++)
                #pragma unroll
                for (int r = 0; r < 4; r++) o[f][r] *= al;
        }
        #pragma unroll
        for (int r = 0; r < 4; r++) {
            ushort4 pk;
            u16 pb[4];
            #pragma unroll
            for (int c = 0; c < 4; c++) {
                float p = __builtin_amdgcn_exp2f(__builtin_fmaf(s[c][r], SC, -mm));
                l_part[r] += p;
                __bf16 hv = (__bf16)p;
                pb[c] = *(u16*)&hv;
            }
            pk.x = pb[0]; pk.y = pb[1]; pk.z = pb[2]; pk.w = pb[3];
            *(ushort4*)(&p_lds[w][lg * 4 + r][lr * 4]) = pk;
        }

        if (it + 1 < 32) {
            asm volatile("s_waitcnt vmcnt(1)" ::: "memory");
        } else {
            asm volatile("s_waitcnt vmcnt(0)" ::: "memory");
        }
        __builtin_amdgcn_sched_barrier(0);
        __builtin_amdgcn_s_barrier();

        __builtin_amdgcn_s_setprio(1);
        #pragma unroll
        for (int kk = 0; kk < 2; kk++) {
            bf16x8 ap = *(const bf16x8*)(&p_lds[w][lr][kk * 32 + lg * 8]);
            #pragma unroll
            for (int f = 0; f < 4; f++) {
                const u16* vrow = vt_lds + (f * 16 + lr) * 64;
                bf16x8 bv = *(const bf16x8*)(vrow + (((kk * 4 + lg) ^ lk)) * 8);
                o[f] = __builtin_amdgcn_mfma_f32_16x16x32_bf16(ap, bv, o[f], 0, 0, 0);
            }
        }
        __builtin_amdgcn_s_setprio(0);

        __syncthreads();
    }

    float invl[4];
    #pragma unroll
    for (int r = 0; r < 4; r++) {
        float lr_ = l_part[r];
        lr_ += __shfl_xor(lr_, 1);
        lr_ += __shfl_xor(lr_, 2);
        lr_ += __shfl_xor(lr_, 4);
        lr_ += __shfl_xor(lr_, 8);
        invl[r] = 1.f / lr_;
    }
    u16* ob = attn_out + ((size_t)b * 2048 + q0 + w * 16 + lg * 4) * 1024 + h * 64 + lr;
    #pragma unroll
    for (int f = 0; f < 4; f++) {
        #pragma unroll
        for (int r = 0; r < 4; r++) {
            __bf16 hv = (__bf16)(o[f][r] * invl[r]);
            ob[(size_t)r * 1024 + f * 16] = *(u16*)&hv;
        }
    }
}

// ---------------- launcher ----------------
extern "C" void kernel_launch(void* const* d_in, const int* in_sizes, int n_in,
                              void* d_out, int out_size, void* d_ws, size_t ws_size,
                              hipStream_t stream) {
    const float* hidden = (const float*)d_in[0];
    const float* enc    = (const float*)d_in[1];
    const float* Wq = (const float*)d_in[2];
    const float* Wk = (const float*)d_in[3];
    const float* Wv = (const float*)d_in[4];
    const float* Wo = (const float*)d_in[5];
    const float* bo = (const float*)d_in[6];
    const float* Wg = (const float*)d_in[7];
    const float* bg = (const float*)d_in[8];
    float* out = (float*)d_out;

    char* ws = (char*)d_ws;
    size_t off = 0;
    auto alloc = [&](size_t bytes) -> char* {
        char* p = ws + off;
        off += (bytes + 255) & ~(size_t)255;
        return p;
    };
    u16* hbf   = (u16*)alloc(4096ull * 1024 * 2);
    u16* ebf   = (u16*)alloc(32768ull * 1024 * 2);
    u16* WqT   = (u16*)alloc(1024ull * 1024 * 2);
    u16* WkvT  = (u16*)alloc(2048ull * 1024 * 2);
    u16* WgT   = (u16*)alloc(1024ull * 1024 * 2);
    u16* WoT   = (u16*)alloc(1024ull * 1024 * 2);
    u16* q_bf  = (u16*)alloc(4096ull * 1024 * 2);
    float* hm  = (float*)alloc(2ull * 1024 * 4);
    float* part = (float*)alloc(2ull * 128 * 1024 * 4);
    u16* z_bf  = (u16*)alloc(32ull * 1024 * 2);
    float* scor = (float*)alloc(32ull * 16384 * 4);
    int* sel    = (int*)alloc(32ull * 2048 * 4);
    u16* ksel   = (u16*)alloc(32ull * 2048 * 64 * 2);
    u16* vT     = (u16*)alloc(32ull * 64 * 2048 * 2);
    u16* attn   = (u16*)alloc(4096ull * 1024 * 2);
    u16* gate   = (u16*)alloc(4096ull * 1024 * 2);
    (void)ws_size; (void)in_sizes; (void)n_in; (void)out_size;

    hsum1_kernel<<<dim3(2, 128), 256, 0, stream>>>(hidden, part);
    hsum2_kernel<<<2, 256, 0, stream>>>(part, hm);
    cast_bf16_kernel<<<4096, 256, 0, stream>>>(hidden, hbf, 1048576);
    transpose_cast_kernel<<<dim3(32, 32, 5), dim3(32, 8), 0, stream>>>(
        Wq, Wk, Wv, Wg, Wo, WqT, WkvT, WgT, WoT);

    qz_kernel<<<32, 256, 0, stream>>>(hm, WqT, WkvT, z_bf);
    escore_kernel<<<dim3(256, 2), 256, 0, stream>>>(enc, z_bf, ebf, scor);
    select_kernel<<<32, 1024, 0, stream>>>(scor, sel);
    selproj_kernel<<<dim3(16, 32), 256, 0, stream>>>(ebf, WkvT, sel, ksel, vT);

    gemm_bf16<0><<<dim3(8, 32), 256, 0, stream>>>(hbf, WqT, 1024, q_bf, nullptr, nullptr, nullptr, nullptr);
    attn_kernel<<<dim3(16, 32), 512, 0, stream>>>(q_bf, ksel, vT, attn);

    gemm_bf16<2><<<dim3(8, 32), 256, 0, stream>>>(attn, WgT, 1024, gate, bg, attn, nullptr, nullptr);
    gemm_bf16<3><<<dim3(8, 32), 256, 0, stream>>>(gate, WoT, 1024, nullptr, bo, nullptr, hidden, out);
}